// Round 2
// baseline (621.390 us; speedup 1.0000x reference)
//
#include <hip/hip_runtime.h>
#include <hip/hip_bf16.h>
#include <math.h>

typedef __attribute__((ext_vector_type(8))) short short8;
typedef __attribute__((ext_vector_type(4))) float f32x4;

#define TT 4096
#define DM 1024
#define NH 16
#define HD 64

// Fused fp32 -> bf16 cast for x (4M el) + Wq/Wk/Wv/Wo (1M el each).
// Block b handles 1024 elements (256 threads x 4).
__global__ __launch_bounds__(256) void cast_all(
    const float* __restrict__ x,  const float* __restrict__ wq,
    const float* __restrict__ wk, const float* __restrict__ wv,
    const float* __restrict__ wo,
    __hip_bfloat16* __restrict__ xb,  __hip_bfloat16* __restrict__ wqb,
    __hip_bfloat16* __restrict__ wkb, __hip_bfloat16* __restrict__ wvb,
    __hip_bfloat16* __restrict__ wob)
{
    int b = blockIdx.x;
    const float* src;
    __hip_bfloat16* dst;
    size_t base;
    if (b < 4096)      { src = x;  dst = xb;  base = (size_t)b * 1024; }
    else if (b < 5120) { src = wq; dst = wqb; base = (size_t)(b - 4096) * 1024; }
    else if (b < 6144) { src = wk; dst = wkb; base = (size_t)(b - 5120) * 1024; }
    else if (b < 7168) { src = wv; dst = wvb; base = (size_t)(b - 6144) * 1024; }
    else               { src = wo; dst = wob; base = (size_t)(b - 7168) * 1024; }
    size_t i = base + (size_t)threadIdx.x * 4;
    float4 v = *(const float4*)(src + i);
    __hip_bfloat16 h0 = (__hip_bfloat16)v.x;
    __hip_bfloat16 h1 = (__hip_bfloat16)v.y;
    __hip_bfloat16 h2 = (__hip_bfloat16)v.z;
    __hip_bfloat16 h3 = (__hip_bfloat16)v.w;
    ushort4 u;
    u.x = *(unsigned short*)&h0;
    u.y = *(unsigned short*)&h1;
    u.z = *(unsigned short*)&h2;
    u.w = *(unsigned short*)&h3;
    *(ushort4*)((unsigned short*)dst + i) = u;
}

// C[M,N] = A[M,K] * B[N,K]^T + bias ; M=4096, N=K=1024 ; bf16 A/B, fp32 acc,
// fp32 bias, OutT output. Wave tile 32x64 (2x4 MFMA 16x16x32), block 64x128.
template <typename OutT>
__global__ __launch_bounds__(256) void gemm_bt(
    const __hip_bfloat16* __restrict__ A,
    const __hip_bfloat16* __restrict__ B,
    const float* __restrict__ bias,
    OutT* __restrict__ C)
{
    const int K = DM;
    const int N = DM;
    const int tid  = threadIdx.x;
    const int wave = tid >> 6;
    const int lane = tid & 63;
    const int l16  = lane & 15;
    const int quad = lane >> 4;
    const int rowBase = blockIdx.x * 64 + (wave & 1) * 32;
    const int colBase = blockIdx.y * 128 + (wave >> 1) * 64;

    f32x4 acc[2][4];
#pragma unroll
    for (int i = 0; i < 2; ++i)
#pragma unroll
        for (int j = 0; j < 4; ++j)
            acc[i][j] = (f32x4){0.f, 0.f, 0.f, 0.f};

    const __hip_bfloat16* a0p = A + (size_t)(rowBase + l16) * K + quad * 8;
    const __hip_bfloat16* a1p = a0p + 16 * K;
    const __hip_bfloat16* b0p = B + (size_t)(colBase + l16) * K + quad * 8;
    const __hip_bfloat16* b1p = b0p + 16 * K;
    const __hip_bfloat16* b2p = b0p + 32 * K;
    const __hip_bfloat16* b3p = b0p + 48 * K;

    for (int k0 = 0; k0 < K; k0 += 32) {
        short8 a0 = *(const short8*)(a0p + k0);
        short8 a1 = *(const short8*)(a1p + k0);
        short8 b0 = *(const short8*)(b0p + k0);
        short8 b1 = *(const short8*)(b1p + k0);
        short8 b2 = *(const short8*)(b2p + k0);
        short8 b3 = *(const short8*)(b3p + k0);
        acc[0][0] = __builtin_amdgcn_mfma_f32_16x16x32_bf16(a0, b0, acc[0][0], 0, 0, 0);
        acc[0][1] = __builtin_amdgcn_mfma_f32_16x16x32_bf16(a0, b1, acc[0][1], 0, 0, 0);
        acc[0][2] = __builtin_amdgcn_mfma_f32_16x16x32_bf16(a0, b2, acc[0][2], 0, 0, 0);
        acc[0][3] = __builtin_amdgcn_mfma_f32_16x16x32_bf16(a0, b3, acc[0][3], 0, 0, 0);
        acc[1][0] = __builtin_amdgcn_mfma_f32_16x16x32_bf16(a1, b0, acc[1][0], 0, 0, 0);
        acc[1][1] = __builtin_amdgcn_mfma_f32_16x16x32_bf16(a1, b1, acc[1][1], 0, 0, 0);
        acc[1][2] = __builtin_amdgcn_mfma_f32_16x16x32_bf16(a1, b2, acc[1][2], 0, 0, 0);
        acc[1][3] = __builtin_amdgcn_mfma_f32_16x16x32_bf16(a1, b3, acc[1][3], 0, 0, 0);
    }

#pragma unroll
    for (int nt = 0; nt < 4; ++nt) {
        int col = colBase + nt * 16 + l16;
        float bv = bias[col];
#pragma unroll
        for (int mt = 0; mt < 2; ++mt) {
#pragma unroll
            for (int r = 0; r < 4; ++r) {
                int row = rowBase + mt * 16 + quad * 4 + r;
                C[(size_t)row * N + col] = (OutT)(acc[mt][nt][r] + bv);
            }
        }
    }
}

// G[t,h] = sigmoid(x[t,:] . Wg[h,:] + bg[h]) ; one wave per token. fp32 in.
__global__ __launch_bounds__(64) void g_kernel(
    const float* __restrict__ x,
    const float* __restrict__ Wg,
    const float* __restrict__ bg,
    float* __restrict__ G)
{
    const int t = blockIdx.x;
    const int lane = threadIdx.x;
    float xv[16];
#pragma unroll
    for (int i = 0; i < 16; ++i) xv[i] = x[(size_t)t * DM + i * 64 + lane];
    float zk = 0.f;
    for (int h = 0; h < NH; ++h) {
        float a = 0.f;
#pragma unroll
        for (int i = 0; i < 16; ++i) a += xv[i] * Wg[(size_t)h * DM + i * 64 + lane];
        for (int off = 32; off; off >>= 1) a += __shfl_xor(a, off);
        if (lane == h) zk = a;
    }
    if (lane < NH) {
        float z = zk + bg[lane];
        G[t * NH + lane] = 1.f / (1.f + __expf(-z));
    }
}

// Chunk means over 32 consecutive tokens: CK[c,:], CV[c,:], c = 0..127.
__global__ __launch_bounds__(256) void chunk_kernel(
    const __hip_bfloat16* __restrict__ K,
    const __hip_bfloat16* __restrict__ V,
    __hip_bfloat16* __restrict__ CK,
    __hip_bfloat16* __restrict__ CV)
{
    const int c = blockIdx.x;
    const int d = blockIdx.y * 256 + threadIdx.x;
    float ak = 0.f, av = 0.f;
    for (int i = 0; i < 32; ++i) {
        ak += (float)K[(size_t)(c * 32 + i) * DM + d];
        av += (float)V[(size_t)(c * 32 + i) * DM + d];
    }
    CK[(size_t)c * DM + d] = (__hip_bfloat16)(ak * (1.f / 32.f));
    CV[(size_t)c * DM + d] = (__hip_bfloat16)(av * (1.f / 32.f));
}

// One wave per (t, h): local softmax over up to 64 prev tokens, remote softmax
// over up to 16 chunk means, mix by gate. Attention excludes token t itself.
__global__ __launch_bounds__(64) void attn_kernel(
    const __hip_bfloat16* __restrict__ Q,
    const __hip_bfloat16* __restrict__ K,
    const __hip_bfloat16* __restrict__ V,
    const __hip_bfloat16* __restrict__ CK,
    const __hip_bfloat16* __restrict__ CV,
    const float* __restrict__ G,
    __hip_bfloat16* __restrict__ Aout)
{
    const int t = blockIdx.x;
    const int h = blockIdx.y;
    const int lane = threadIdx.x;
    const float scale = 0.125f; // 1/sqrt(64)

    __shared__ float Ks[64 * 65];
    __shared__ float Cs[16 * 65];
    __shared__ float qs[64];
    __shared__ float ps[64];
    __shared__ float ps2[64];

    const size_t hoff = (size_t)h * HD;
    qs[lane] = (float)Q[(size_t)t * DM + hoff + lane];

    const int nloc = t < 64 ? t : 64;      // valid local keys
    const int j0 = 64 - nloc;              // lanes [j0,64) hold valid keys
    for (int r = j0; r < 64; ++r) {
        int tok = t - 64 + r;
        Ks[r * 65 + lane] = (float)K[(size_t)tok * DM + hoff + lane];
    }
    const int rc = (t >= 96) ? ((t - 64) >> 5) : 0;  // completed chunks visible at t
    const int nvis = rc < 16 ? rc : 16;
    const int c0 = rc - nvis;
    for (int r = 0; r < nvis; ++r) {
        Cs[r * 65 + lane] = (float)CK[(size_t)(c0 + r) * DM + hoff + lane];
    }
    __syncthreads();

    // local scores: lane j owns key j
    float s = -1e30f;
    if (lane >= j0) {
        float a = 0.f;
        for (int d = 0; d < 64; ++d) a += qs[d] * Ks[lane * 65 + d];
        s = a * scale;
    }
    float mx = s;
    for (int off = 32; off; off >>= 1) mx = fmaxf(mx, __shfl_xor(mx, off));
    float p = (lane >= j0) ? __expf(s - mx) : 0.f;
    float sm = p;
    for (int off = 32; off; off >>= 1) sm += __shfl_xor(sm, off);
    p = (nloc > 0) ? p / sm : 0.f;

    // remote scores: lane j < nvis owns chunk c0+j
    float s2 = -1e30f;
    if (lane < nvis) {
        float a = 0.f;
        for (int d = 0; d < 64; ++d) a += qs[d] * Cs[lane * 65 + d];
        s2 = a * scale;
    }
    float mx2 = s2;
    for (int off = 32; off; off >>= 1) mx2 = fmaxf(mx2, __shfl_xor(mx2, off));
    float p2 = (lane < nvis) ? __expf(s2 - mx2) : 0.f;
    float sm2 = p2;
    for (int off = 32; off; off >>= 1) sm2 += __shfl_xor(sm2, off);
    p2 = (nvis > 0) ? p2 / sm2 : 0.f;

    ps[lane] = p;
    ps2[lane] = p2;
    __syncthreads();

    // PV: lane d accumulates output dim d (coalesced V reads)
    float lo = 0.f;
    for (int r = j0; r < 64; ++r) {
        int tok = t - 64 + r;
        lo += ps[r] * (float)V[(size_t)tok * DM + hoff + lane];
    }
    float ro = 0.f;
    for (int r = 0; r < nvis; ++r) {
        ro += ps2[r] * (float)CV[(size_t)(c0 + r) * DM + hoff + lane];
    }
    float g = G[t * NH + h];
    float outv = g * lo + (1.f - g) * ro;
    Aout[(size_t)t * DM + hoff + lane] = (__hip_bfloat16)outv;
}

extern "C" void kernel_launch(void* const* d_in, const int* in_sizes, int n_in,
                              void* d_out, int out_size, void* d_ws, size_t ws_size,
                              hipStream_t stream)
{
    const float* x  = (const float*)d_in[0];
    const float* Wq = (const float*)d_in[1];
    const float* bq = (const float*)d_in[2];
    const float* Wk = (const float*)d_in[3];
    const float* bk = (const float*)d_in[4];
    const float* Wv = (const float*)d_in[5];
    const float* bv = (const float*)d_in[6];
    const float* Wo = (const float*)d_in[7];
    const float* bo = (const float*)d_in[8];
    const float* Wg = (const float*)d_in[9];
    const float* bg = (const float*)d_in[10];
    float* out = (float*)d_out;

    char* ws = (char*)d_ws;
    const size_t MB = 1024 * 1024;
    __hip_bfloat16* xb  = (__hip_bfloat16*)(ws + 0 * MB);   // 8 MB
    __hip_bfloat16* Qb  = (__hip_bfloat16*)(ws + 8 * MB);   // 8 MB
    __hip_bfloat16* Kb  = (__hip_bfloat16*)(ws + 16 * MB);  // 8 MB
    __hip_bfloat16* Vb  = (__hip_bfloat16*)(ws + 24 * MB);  // 8 MB
    __hip_bfloat16* Ab  = (__hip_bfloat16*)(ws + 32 * MB);  // 8 MB
    __hip_bfloat16* Wqb = (__hip_bfloat16*)(ws + 40 * MB);  // 2 MB
    __hip_bfloat16* Wkb = (__hip_bfloat16*)(ws + 42 * MB);  // 2 MB
    __hip_bfloat16* Wvb = (__hip_bfloat16*)(ws + 44 * MB);  // 2 MB
    __hip_bfloat16* Wob = (__hip_bfloat16*)(ws + 46 * MB);  // 2 MB
    __hip_bfloat16* CKb = (__hip_bfloat16*)(ws + 48 * MB);            // 256 KB
    __hip_bfloat16* CVb = (__hip_bfloat16*)(ws + 48 * MB + 256*1024); // 256 KB
    float* Gf           = (float*)(ws + 48 * MB + 512 * 1024);        // 256 KB

    cast_all<<<dim3(8192), 256, 0, stream>>>(x, Wq, Wk, Wv, Wo, xb, Wqb, Wkb, Wvb, Wob);

    dim3 ggrid(64, 8);
    gemm_bt<__hip_bfloat16><<<ggrid, 256, 0, stream>>>(xb, Wqb, bq, Qb);
    gemm_bt<__hip_bfloat16><<<ggrid, 256, 0, stream>>>(xb, Wkb, bk, Kb);
    gemm_bt<__hip_bfloat16><<<ggrid, 256, 0, stream>>>(xb, Wvb, bv, Vb);
    g_kernel<<<dim3(TT), 64, 0, stream>>>(x, Wg, bg, Gf);
    chunk_kernel<<<dim3(128, 4), 256, 0, stream>>>(Kb, Vb, CKb, CVb);
    attn_kernel<<<dim3(TT, NH), 64, 0, stream>>>(Qb, Kb, Vb, CKb, CVb, Gf, Ab);
    gemm_bt<float><<<ggrid, 256, 0, stream>>>(Ab, Wob, bo, out);
}

// Round 4
// 324.660 us; speedup vs baseline: 1.9140x; 1.9140x over previous
//
#include <hip/hip_runtime.h>
#include <hip/hip_bf16.h>
#include <math.h>

typedef __attribute__((ext_vector_type(8))) short short8;
typedef __attribute__((ext_vector_type(4))) float f32x4;

#define TT 4096
#define DM 1024
#define NH 16
#define HD 64
#define PSTR 168   // LDS row stride in halfwords (160 slots + 8 pad; 336 B = 84 dwords == 20 mod 32 banks)

// Fused fp32 -> bf16 cast for x (4M el) + Wq/Wk/Wv/Wo (1M el each).
__global__ __launch_bounds__(256) void cast_all(
    const float* __restrict__ x,  const float* __restrict__ wq,
    const float* __restrict__ wk, const float* __restrict__ wv,
    const float* __restrict__ wo,
    __hip_bfloat16* __restrict__ xb,  __hip_bfloat16* __restrict__ wqb,
    __hip_bfloat16* __restrict__ wkb, __hip_bfloat16* __restrict__ wvb,
    __hip_bfloat16* __restrict__ wob)
{
    int b = blockIdx.x;
    const float* src;
    __hip_bfloat16* dst;
    size_t base;
    if (b < 4096)      { src = x;  dst = xb;  base = (size_t)b * 1024; }
    else if (b < 5120) { src = wq; dst = wqb; base = (size_t)(b - 4096) * 1024; }
    else if (b < 6144) { src = wk; dst = wkb; base = (size_t)(b - 5120) * 1024; }
    else if (b < 7168) { src = wv; dst = wvb; base = (size_t)(b - 6144) * 1024; }
    else               { src = wo; dst = wob; base = (size_t)(b - 7168) * 1024; }
    size_t i = base + (size_t)threadIdx.x * 4;
    float4 v = *(const float4*)(src + i);
    __hip_bfloat16 h0 = (__hip_bfloat16)v.x;
    __hip_bfloat16 h1 = (__hip_bfloat16)v.y;
    __hip_bfloat16 h2 = (__hip_bfloat16)v.z;
    __hip_bfloat16 h3 = (__hip_bfloat16)v.w;
    ushort4 u;
    u.x = *(unsigned short*)&h0;
    u.y = *(unsigned short*)&h1;
    u.z = *(unsigned short*)&h2;
    u.w = *(unsigned short*)&h3;
    *(ushort4*)((unsigned short*)dst + i) = u;
}

// C[M,N] = A[M,K] * B[N,K]^T + bias ; bf16 A/B, fp32 acc, fp32 bias, OutT out.
template <typename OutT>
__global__ __launch_bounds__(256) void gemm_bt(
    const __hip_bfloat16* __restrict__ A,
    const __hip_bfloat16* __restrict__ B,
    const float* __restrict__ bias,
    OutT* __restrict__ C)
{
    const int K = DM;
    const int N = DM;
    const int tid  = threadIdx.x;
    const int wave = tid >> 6;
    const int lane = tid & 63;
    const int l16  = lane & 15;
    const int quad = lane >> 4;
    const int rowBase = blockIdx.x * 64 + (wave & 1) * 32;
    const int colBase = blockIdx.y * 128 + (wave >> 1) * 64;

    f32x4 acc[2][4];
#pragma unroll
    for (int i = 0; i < 2; ++i)
#pragma unroll
        for (int j = 0; j < 4; ++j)
            acc[i][j] = (f32x4){0.f, 0.f, 0.f, 0.f};

    const __hip_bfloat16* a0p = A + (size_t)(rowBase + l16) * K + quad * 8;
    const __hip_bfloat16* a1p = a0p + 16 * K;
    const __hip_bfloat16* b0p = B + (size_t)(colBase + l16) * K + quad * 8;
    const __hip_bfloat16* b1p = b0p + 16 * K;
    const __hip_bfloat16* b2p = b0p + 32 * K;
    const __hip_bfloat16* b3p = b0p + 48 * K;

    for (int k0 = 0; k0 < K; k0 += 32) {
        short8 a0 = *(const short8*)(a0p + k0);
        short8 a1 = *(const short8*)(a1p + k0);
        short8 b0 = *(const short8*)(b0p + k0);
        short8 b1 = *(const short8*)(b1p + k0);
        short8 b2 = *(const short8*)(b2p + k0);
        short8 b3 = *(const short8*)(b3p + k0);
        acc[0][0] = __builtin_amdgcn_mfma_f32_16x16x32_bf16(a0, b0, acc[0][0], 0, 0, 0);
        acc[0][1] = __builtin_amdgcn_mfma_f32_16x16x32_bf16(a0, b1, acc[0][1], 0, 0, 0);
        acc[0][2] = __builtin_amdgcn_mfma_f32_16x16x32_bf16(a0, b2, acc[0][2], 0, 0, 0);
        acc[0][3] = __builtin_amdgcn_mfma_f32_16x16x32_bf16(a0, b3, acc[0][3], 0, 0, 0);
        acc[1][0] = __builtin_amdgcn_mfma_f32_16x16x32_bf16(a1, b0, acc[1][0], 0, 0, 0);
        acc[1][1] = __builtin_amdgcn_mfma_f32_16x16x32_bf16(a1, b1, acc[1][1], 0, 0, 0);
        acc[1][2] = __builtin_amdgcn_mfma_f32_16x16x32_bf16(a1, b2, acc[1][2], 0, 0, 0);
        acc[1][3] = __builtin_amdgcn_mfma_f32_16x16x32_bf16(a1, b3, acc[1][3], 0, 0, 0);
    }

#pragma unroll
    for (int nt = 0; nt < 4; ++nt) {
        int col = colBase + nt * 16 + l16;
        float bv = bias[col];
#pragma unroll
        for (int mt = 0; mt < 2; ++mt) {
#pragma unroll
            for (int r = 0; r < 4; ++r) {
                int row = rowBase + mt * 16 + quad * 4 + r;
                C[(size_t)row * N + col] = (OutT)(acc[mt][nt][r] + bv);
            }
        }
    }
}

// G[t,h] = sigmoid(x[t,:] . Wg[h,:] + bg[h]) ; one wave per token. fp32 in.
__global__ __launch_bounds__(64) void g_kernel(
    const float* __restrict__ x,
    const float* __restrict__ Wg,
    const float* __restrict__ bg,
    float* __restrict__ G)
{
    const int t = blockIdx.x;
    const int lane = threadIdx.x;
    float xv[16];
#pragma unroll
    for (int i = 0; i < 16; ++i) xv[i] = x[(size_t)t * DM + i * 64 + lane];
    float zk = 0.f;
    for (int h = 0; h < NH; ++h) {
        float a = 0.f;
#pragma unroll
        for (int i = 0; i < 16; ++i) a += xv[i] * Wg[(size_t)h * DM + i * 64 + lane];
        for (int off = 32; off; off >>= 1) a += __shfl_xor(a, off);
        if (lane == h) zk = a;
    }
    if (lane < NH) {
        float z = zk + bg[lane];
        G[t * NH + lane] = 1.f / (1.f + __expf(-z));
    }
}

// Chunk means over 32 consecutive tokens: CK[c,:], CV[c,:], c = 0..127.
__global__ __launch_bounds__(256) void chunk_kernel(
    const __hip_bfloat16* __restrict__ K,
    const __hip_bfloat16* __restrict__ V,
    __hip_bfloat16* __restrict__ CK,
    __hip_bfloat16* __restrict__ CV)
{
    const int c = blockIdx.x;
    const int d = blockIdx.y * 256 + threadIdx.x;
    float ak = 0.f, av = 0.f;
    for (int i = 0; i < 32; ++i) {
        ak += (float)K[(size_t)(c * 32 + i) * DM + d];
        av += (float)V[(size_t)(c * 32 + i) * DM + d];
    }
    CK[(size_t)c * DM + d] = (__hip_bfloat16)(ak * (1.f / 32.f));
    CV[(size_t)c * DM + d] = (__hip_bfloat16)(av * (1.f / 32.f));
}

// MFMA attention: 64 queries x 1 head per block (grid 64 x 16, 256 threads).
// Local window = 128 key slots (tokens t0-64 .. t0+62, banded mask per query);
// remote = 32 chunk slots (union of per-query 16-chunk windows). Gate folded
// into P, local+remote PV fused into one MFMA chain over 160 slots.
// No LDS swizzle: PSTR row stride (84 dwords == 20 mod 32) staggers banks.
__global__ __launch_bounds__(256) void attn_mfma(
    const __hip_bfloat16* __restrict__ Q,
    const __hip_bfloat16* __restrict__ K,
    const __hip_bfloat16* __restrict__ V,
    const __hip_bfloat16* __restrict__ CK,
    const __hip_bfloat16* __restrict__ CV,
    const float* __restrict__ G,
    __hip_bfloat16* __restrict__ Aout)
{
    __shared__ alignas(16) unsigned short Pls[64 * PSTR];  // P (64 queries x 160 slots, bf16)
    __shared__ alignas(16) unsigned short Vts[64 * PSTR];  // V^T (64 dims x 160 slots, bf16)

    const int h   = blockIdx.y;
    const int t0  = blockIdx.x * 64;
    const int tid = threadIdx.x;
    const int w    = tid >> 6;
    const int lane = tid & 63;
    const int l16  = lane & 15;
    const int quad = lane >> 4;
    const float scale = 0.125f;

    const int rc0  = (t0 >= 96) ? ((t0 - 64) >> 5) : 0;
    const int cmin = rc0 > 16 ? rc0 - 16 : 0;

    const unsigned short* Vu  = (const unsigned short*)V;
    const unsigned short* CVu = (const unsigned short*)CV;

    // ---- stage V^T (+ CV^T) into LDS: slot j in [0,160), dim d = lane ----
    {
        const int d = lane;
#pragma unroll
        for (int i = 0; i < 20; ++i) {
            int p = w * 20 + i;           // pair index 0..79
            int j = p * 2;
            unsigned short v0, v1;
            if (j < 128) {
                int tok0 = t0 - 64 + j;
                int tok1 = tok0 + 1;
                tok0 = tok0 < 0 ? 0 : tok0;
                tok1 = tok1 < 0 ? 0 : tok1;
                v0 = Vu[(size_t)tok0 * DM + h * 64 + d];
                v1 = Vu[(size_t)tok1 * DM + h * 64 + d];
            } else {
                int n0 = j - 128;
                int c0 = cmin + n0;     if (c0 > 127) c0 = 127;
                int c1 = cmin + n0 + 1; if (c1 > 127) c1 = 127;
                v0 = CVu[(size_t)c0 * DM + h * 64 + d];
                v1 = CVu[(size_t)c1 * DM + h * 64 + d];
            }
            *(ushort2*)&Vts[d * PSTR + j] = (ushort2){v0, v1};
        }
    }

    // ---- Q A-fragments (direct global) ----
    const __hip_bfloat16* qp = Q + (size_t)(t0 + w * 16 + l16) * DM + h * 64 + quad * 8;
    short8 qf0 = *(const short8*)(qp);
    short8 qf1 = *(const short8*)(qp + 32);

    // ---- local scores: 8 key tiles ----
    f32x4 sc[8];
#pragma unroll
    for (int jt = 0; jt < 8; ++jt) {
        int j = jt * 16 + l16;
        int tok = t0 - 64 + j;
        tok = tok < 0 ? 0 : tok;
        const __hip_bfloat16* kp = K + (size_t)tok * DM + h * 64 + quad * 8;
        short8 b0 = *(const short8*)(kp);
        short8 b1 = *(const short8*)(kp + 32);
        f32x4 a = __builtin_amdgcn_mfma_f32_16x16x32_bf16(qf0, b0, (f32x4){0.f,0.f,0.f,0.f}, 0, 0, 0);
        sc[jt]  = __builtin_amdgcn_mfma_f32_16x16x32_bf16(qf1, b1, a, 0, 0, 0);
    }
    // ---- remote scores: 2 chunk tiles ----
    f32x4 sc2[2];
#pragma unroll
    for (int jt = 0; jt < 2; ++jt) {
        int c = cmin + jt * 16 + l16;
        if (c > 127) c = 127;
        const __hip_bfloat16* cp = CK + (size_t)c * DM + h * 64 + quad * 8;
        short8 b0 = *(const short8*)(cp);
        short8 b1 = *(const short8*)(cp + 32);
        f32x4 a = __builtin_amdgcn_mfma_f32_16x16x32_bf16(qf0, b0, (f32x4){0.f,0.f,0.f,0.f}, 0, 0, 0);
        sc2[jt] = __builtin_amdgcn_mfma_f32_16x16x32_bf16(qf1, b1, a, 0, 0, 0);
    }

    __syncthreads();  // Vts ready for all waves

    // ---- masked softmax (rows live on fixed quad; columns = l16 x tile regs) ----
    const int rbase = w * 16 + quad * 4;   // query row of reg 0
    float gl[4], g2[4];
    float mx[4], sm[4], mx2[4], sm2[4];
#pragma unroll
    for (int reg = 0; reg < 4; ++reg) {
        int rr = rbase + reg;
        int t  = t0 + rr;
        float g = G[t * NH + h];
        int rc = (t >= 96) ? ((t - 64) >> 5) : 0;
        gl[reg] = (t > 0)  ? g        : 0.f;
        g2[reg] = (rc > 0) ? (1.f - g) : 0.f;

        int jlo = rr > (64 - t0) ? rr : (64 - t0);
        int jhi = rr + 63;
        float m = -1e30f;
#pragma unroll
        for (int jt = 0; jt < 8; ++jt) {
            int j = jt * 16 + l16;
            float s = (j >= jlo && j <= jhi) ? sc[jt][reg] * scale : -1e30f;
            sc[jt][reg] = s;
            m = fmaxf(m, s);
        }
        mx[reg] = m;

        int nvis = rc < 16 ? rc : 16;
        int clo = rc - nvis, chi = rc - 1;
        float m2 = -1e30f;
#pragma unroll
        for (int jt = 0; jt < 2; ++jt) {
            int c = cmin + jt * 16 + l16;
            float s = (c >= clo && c <= chi) ? sc2[jt][reg] * scale : -1e30f;
            sc2[jt][reg] = s;
            m2 = fmaxf(m2, s);
        }
        mx2[reg] = m2;
    }
#pragma unroll
    for (int off = 1; off <= 8; off <<= 1)
#pragma unroll
        for (int reg = 0; reg < 4; ++reg) {
            mx[reg]  = fmaxf(mx[reg],  __shfl_xor(mx[reg],  off));
            mx2[reg] = fmaxf(mx2[reg], __shfl_xor(mx2[reg], off));
        }
#pragma unroll
    for (int reg = 0; reg < 4; ++reg) {
        float s = 0.f, s2 = 0.f;
#pragma unroll
        for (int jt = 0; jt < 8; ++jt) {
            float p = __expf(sc[jt][reg] - mx[reg]);
            sc[jt][reg] = p;
            s += p;
        }
#pragma unroll
        for (int jt = 0; jt < 2; ++jt) {
            float p = __expf(sc2[jt][reg] - mx2[reg]);
            sc2[jt][reg] = p;
            s2 += p;
        }
        sm[reg] = s; sm2[reg] = s2;
    }
#pragma unroll
    for (int off = 1; off <= 8; off <<= 1)
#pragma unroll
        for (int reg = 0; reg < 4; ++reg) {
            sm[reg]  += __shfl_xor(sm[reg],  off);
            sm2[reg] += __shfl_xor(sm2[reg], off);
        }

    // ---- write gated P to LDS (bf16) ----
#pragma unroll
    for (int reg = 0; reg < 4; ++reg) {
        float f1 = gl[reg] / sm[reg];
        float f2 = g2[reg] / sm2[reg];
        int rowoff = (rbase + reg) * PSTR;
#pragma unroll
        for (int jt = 0; jt < 8; ++jt) {
            __hip_bfloat16 hb = (__hip_bfloat16)(sc[jt][reg] * f1);
            Pls[rowoff + jt * 16 + l16] = *(unsigned short*)&hb;
        }
#pragma unroll
        for (int jt = 0; jt < 2; ++jt) {
            __hip_bfloat16 hb = (__hip_bfloat16)(sc2[jt][reg] * f2);
            Pls[rowoff + 128 + jt * 16 + l16] = *(unsigned short*)&hb;
        }
    }
    asm volatile("s_waitcnt lgkmcnt(0)" ::: "memory");  // wave-private P round-trip

    // ---- PV: O(16x64 per wave) over 160 slots ----
    f32x4 o[4];
#pragma unroll
    for (int nt = 0; nt < 4; ++nt) o[nt] = (f32x4){0.f, 0.f, 0.f, 0.f};
#pragma unroll
    for (int kt = 0; kt < 5; ++kt) {
        short8 a = *(const short8*)&Pls[(w * 16 + l16) * PSTR + kt * 32 + quad * 8];
#pragma unroll
        for (int nt = 0; nt < 4; ++nt) {
            int dd = nt * 16 + l16;
            short8 b = *(const short8*)&Vts[dd * PSTR + kt * 32 + quad * 8];
            o[nt] = __builtin_amdgcn_mfma_f32_16x16x32_bf16(a, b, o[nt], 0, 0, 0);
        }
    }

#pragma unroll
    for (int nt = 0; nt < 4; ++nt) {
#pragma unroll
        for (int reg = 0; reg < 4; ++reg) {
            int row = t0 + rbase + reg;
            int col = h * 64 + nt * 16 + l16;
            Aout[(size_t)row * DM + col] = (__hip_bfloat16)(o[nt][reg]);
        }
    }
}

extern "C" void kernel_launch(void* const* d_in, const int* in_sizes, int n_in,
                              void* d_out, int out_size, void* d_ws, size_t ws_size,
                              hipStream_t stream)
{
    const float* x  = (const float*)d_in[0];
    const float* Wq = (const float*)d_in[1];
    const float* bq = (const float*)d_in[2];
    const float* Wk = (const float*)d_in[3];
    const float* bk = (const float*)d_in[4];
    const float* Wv = (const float*)d_in[5];
    const float* bv = (const float*)d_in[6];
    const float* Wo = (const float*)d_in[7];
    const float* bo = (const float*)d_in[8];
    const float* Wg = (const float*)d_in[9];
    const float* bg = (const float*)d_in[10];
    float* out = (float*)d_out;

    char* ws = (char*)d_ws;
    const size_t MB = 1024 * 1024;
    __hip_bfloat16* xb  = (__hip_bfloat16*)(ws + 0 * MB);   // 8 MB
    __hip_bfloat16* Qb  = (__hip_bfloat16*)(ws + 8 * MB);   // 8 MB
    __hip_bfloat16* Kb  = (__hip_bfloat16*)(ws + 16 * MB);  // 8 MB
    __hip_bfloat16* Vb  = (__hip_bfloat16*)(ws + 24 * MB);  // 8 MB
    __hip_bfloat16* Ab  = (__hip_bfloat16*)(ws + 32 * MB);  // 8 MB
    __hip_bfloat16* Wqb = (__hip_bfloat16*)(ws + 40 * MB);  // 2 MB
    __hip_bfloat16* Wkb = (__hip_bfloat16*)(ws + 42 * MB);  // 2 MB
    __hip_bfloat16* Wvb = (__hip_bfloat16*)(ws + 44 * MB);  // 2 MB
    __hip_bfloat16* Wob = (__hip_bfloat16*)(ws + 46 * MB);  // 2 MB
    __hip_bfloat16* CKb = (__hip_bfloat16*)(ws + 48 * MB);            // 256 KB
    __hip_bfloat16* CVb = (__hip_bfloat16*)(ws + 48 * MB + 256*1024); // 256 KB
    float* Gf           = (float*)(ws + 48 * MB + 512 * 1024);        // 256 KB

    cast_all<<<dim3(8192), 256, 0, stream>>>(x, Wq, Wk, Wv, Wo, xb, Wqb, Wkb, Wvb, Wob);

    dim3 ggrid(64, 8);
    gemm_bt<__hip_bfloat16><<<ggrid, 256, 0, stream>>>(xb, Wqb, bq, Qb);
    gemm_bt<__hip_bfloat16><<<ggrid, 256, 0, stream>>>(xb, Wkb, bk, Kb);
    gemm_bt<__hip_bfloat16><<<ggrid, 256, 0, stream>>>(xb, Wvb, bv, Vb);
    g_kernel<<<dim3(TT), 64, 0, stream>>>(x, Wg, bg, Gf);
    chunk_kernel<<<dim3(128, 4), 256, 0, stream>>>(Kb, Vb, CKb, CVb);
    attn_mfma<<<dim3(64, 16), 256, 0, stream>>>(Qb, Kb, Vb, CKb, CVb, Gf, Ab);
    gemm_bt<float><<<ggrid, 256, 0, stream>>>(Ab, Wob, bo, out);
}

// Round 5
// 194.493 us; speedup vs baseline: 3.1949x; 1.6693x over previous
//
#include <hip/hip_runtime.h>
#include <hip/hip_bf16.h>
#include <math.h>

typedef __attribute__((ext_vector_type(8))) short short8;
typedef __attribute__((ext_vector_type(4))) float f32x4;

#define TT 4096
#define DM 1024
#define NH 16
#define HD 64
#define PSTR 168   // attn LDS row stride in halfwords

typedef __attribute__((address_space(3))) unsigned int lds_u32;
typedef __attribute__((address_space(1))) unsigned int glb_u32;

__device__ __forceinline__ void async_cp16(const void* g, void* l) {
    __builtin_amdgcn_global_load_lds((glb_u32*)g, (lds_u32*)l, 16, 0, 0);
}

// Fused fp32 -> bf16 cast for x (4M el) + Wq/Wk/Wv/Wo (1M el each).
__global__ __launch_bounds__(256) void cast_all(
    const float* __restrict__ x,  const float* __restrict__ wq,
    const float* __restrict__ wk, const float* __restrict__ wv,
    const float* __restrict__ wo,
    __hip_bfloat16* __restrict__ xb,  __hip_bfloat16* __restrict__ wqb,
    __hip_bfloat16* __restrict__ wkb, __hip_bfloat16* __restrict__ wvb,
    __hip_bfloat16* __restrict__ wob)
{
    int b = blockIdx.x;
    const float* src;
    __hip_bfloat16* dst;
    size_t base;
    if (b < 4096)      { src = x;  dst = xb;  base = (size_t)b * 1024; }
    else if (b < 5120) { src = wq; dst = wqb; base = (size_t)(b - 4096) * 1024; }
    else if (b < 6144) { src = wk; dst = wkb; base = (size_t)(b - 5120) * 1024; }
    else if (b < 7168) { src = wv; dst = wvb; base = (size_t)(b - 6144) * 1024; }
    else               { src = wo; dst = wob; base = (size_t)(b - 7168) * 1024; }
    size_t i = base + (size_t)threadIdx.x * 4;
    float4 v = *(const float4*)(src + i);
    __hip_bfloat16 h0 = (__hip_bfloat16)v.x;
    __hip_bfloat16 h1 = (__hip_bfloat16)v.y;
    __hip_bfloat16 h2 = (__hip_bfloat16)v.z;
    __hip_bfloat16 h3 = (__hip_bfloat16)v.w;
    ushort4 u;
    u.x = *(unsigned short*)&h0;
    u.y = *(unsigned short*)&h1;
    u.z = *(unsigned short*)&h2;
    u.w = *(unsigned short*)&h3;
    *(ushort4*)((unsigned short*)dst + i) = u;
}

// 128x128-tile GEMM, C[M,N] = A[M,K]*B[N,K]^T + bias. bf16 in, fp32 acc.
// Grid (M/128, 8*ngroups): group = blockIdx.y>>3 selects B/bias/O (QKV fusion).
// global_load_lds width-16 staging; k-chunk XOR-swizzled by row so the
// ds_read_b128 fragment reads alias at most 2-way (free) with zero padding.
template <typename OutT>
__global__ __launch_bounds__(256) void gemm128(
    const __hip_bfloat16* __restrict__ A,
    const __hip_bfloat16* __restrict__ B0, const __hip_bfloat16* __restrict__ B1,
    const __hip_bfloat16* __restrict__ B2,
    const float* __restrict__ c0, const float* __restrict__ c1, const float* __restrict__ c2,
    OutT* __restrict__ O0, OutT* __restrict__ O1, OutT* __restrict__ O2)
{
    const int K = DM;
    __shared__ __align__(16) unsigned short sA[128 * 32];
    __shared__ __align__(16) unsigned short sB[128 * 32];

    const int grp = blockIdx.y >> 3;
    const __hip_bfloat16* B = grp == 0 ? B0 : (grp == 1 ? B1 : B2);
    const float* bias       = grp == 0 ? c0 : (grp == 1 ? c1 : c2);
    OutT* O                 = grp == 0 ? O0 : (grp == 1 ? O1 : O2);

    const int tid  = threadIdx.x;
    const int w    = tid >> 6;
    const int lane = tid & 63;
    const int l16  = lane & 15;
    const int quad = lane >> 4;
    const int rowBase = blockIdx.x * 128;
    const int colBase = (blockIdx.y & 7) * 128;

    // staging map: lane -> (srow = lane>>2, slot = lane&3); fetch global chunk slot^s(srow)
    const int srow   = lane >> 2;
    const int sswz   = (srow & 3) ^ (srow >> 2);
    const int gchunk = (lane & 3) ^ sswz;
    const __hip_bfloat16* gA = A + (size_t)(rowBase + w * 32 + srow) * K + gchunk * 8;
    const __hip_bfloat16* gB = B + (size_t)(colBase + w * 32 + srow) * K + gchunk * 8;
    unsigned short* lA = sA + w * 32 * 32;
    unsigned short* lB = sB + w * 32 * 32;

    // fragment read swizzle (row = base16 + l16 -> s depends only on l16)
    const int fswz = (l16 & 3) ^ (l16 >> 2);
    const int mrow = (w & 1) * 64;
    const int ncol = (w >> 1) * 64;

    f32x4 acc[4][4];
#pragma unroll
    for (int i = 0; i < 4; ++i)
#pragma unroll
        for (int j = 0; j < 4; ++j) acc[i][j] = (f32x4){0.f, 0.f, 0.f, 0.f};

    for (int k0 = 0; k0 < K; k0 += 32) {
        __syncthreads();
        async_cp16(gA + k0, lA);
        async_cp16(gA + k0 + (size_t)16 * K, lA + 16 * 32);
        async_cp16(gB + k0, lB);
        async_cp16(gB + k0 + (size_t)16 * K, lB + 16 * 32);
        __syncthreads();

        short8 af[4], bf[4];
#pragma unroll
        for (int mt = 0; mt < 4; ++mt)
            af[mt] = *(const short8*)&sA[(mrow + mt * 16 + l16) * 32 + (quad ^ fswz) * 8];
#pragma unroll
        for (int nt = 0; nt < 4; ++nt)
            bf[nt] = *(const short8*)&sB[(ncol + nt * 16 + l16) * 32 + (quad ^ fswz) * 8];
#pragma unroll
        for (int mt = 0; mt < 4; ++mt)
#pragma unroll
            for (int nt = 0; nt < 4; ++nt)
                acc[mt][nt] = __builtin_amdgcn_mfma_f32_16x16x32_bf16(af[mt], bf[nt], acc[mt][nt], 0, 0, 0);
    }

#pragma unroll
    for (int nt = 0; nt < 4; ++nt) {
        int col = colBase + ncol + nt * 16 + l16;
        float bv = bias[col];
#pragma unroll
        for (int mt = 0; mt < 4; ++mt) {
#pragma unroll
            for (int r = 0; r < 4; ++r) {
                int row = rowBase + mrow + mt * 16 + quad * 4 + r;
                O[(size_t)row * DM + col] = (OutT)(acc[mt][nt][r] + bv);
            }
        }
    }
}

// G[t,h] = sigmoid(x[t,:] . Wg[h,:] + bg[h]) ; one wave per token. fp32 in.
__global__ __launch_bounds__(64) void g_kernel(
    const float* __restrict__ x,
    const float* __restrict__ Wg,
    const float* __restrict__ bg,
    float* __restrict__ G)
{
    const int t = blockIdx.x;
    const int lane = threadIdx.x;
    float xv[16];
#pragma unroll
    for (int i = 0; i < 16; ++i) xv[i] = x[(size_t)t * DM + i * 64 + lane];
    float zk = 0.f;
    for (int h = 0; h < NH; ++h) {
        float a = 0.f;
#pragma unroll
        for (int i = 0; i < 16; ++i) a += xv[i] * Wg[(size_t)h * DM + i * 64 + lane];
        for (int off = 32; off; off >>= 1) a += __shfl_xor(a, off);
        if (lane == h) zk = a;
    }
    if (lane < NH) {
        float z = zk + bg[lane];
        G[t * NH + lane] = 1.f / (1.f + __expf(-z));
    }
}

// Chunk means over 32 consecutive tokens: CK[c,:], CV[c,:], c = 0..127.
__global__ __launch_bounds__(256) void chunk_kernel(
    const __hip_bfloat16* __restrict__ K,
    const __hip_bfloat16* __restrict__ V,
    __hip_bfloat16* __restrict__ CK,
    __hip_bfloat16* __restrict__ CV)
{
    const int c = blockIdx.x;
    const int d = blockIdx.y * 256 + threadIdx.x;
    float ak = 0.f, av = 0.f;
    for (int i = 0; i < 32; ++i) {
        ak += (float)K[(size_t)(c * 32 + i) * DM + d];
        av += (float)V[(size_t)(c * 32 + i) * DM + d];
    }
    CK[(size_t)c * DM + d] = (__hip_bfloat16)(ak * (1.f / 32.f));
    CV[(size_t)c * DM + d] = (__hip_bfloat16)(av * (1.f / 32.f));
}

// MFMA attention: 64 queries x 1 head per block (grid 64 x 16, 256 threads).
__global__ __launch_bounds__(256) void attn_mfma(
    const __hip_bfloat16* __restrict__ Q,
    const __hip_bfloat16* __restrict__ K,
    const __hip_bfloat16* __restrict__ V,
    const __hip_bfloat16* __restrict__ CK,
    const __hip_bfloat16* __restrict__ CV,
    const float* __restrict__ G,
    __hip_bfloat16* __restrict__ Aout)
{
    __shared__ alignas(16) unsigned short Pls[64 * PSTR];
    __shared__ alignas(16) unsigned short Vts[64 * PSTR];

    const int h   = blockIdx.y;
    const int t0  = blockIdx.x * 64;
    const int tid = threadIdx.x;
    const int w    = tid >> 6;
    const int lane = tid & 63;
    const int l16  = lane & 15;
    const int quad = lane >> 4;
    const float scale = 0.125f;

    const int rc0  = (t0 >= 96) ? ((t0 - 64) >> 5) : 0;
    const int cmin = rc0 > 16 ? rc0 - 16 : 0;

    const unsigned short* Vu  = (const unsigned short*)V;
    const unsigned short* CVu = (const unsigned short*)CV;

    {
        const int d = lane;
#pragma unroll
        for (int i = 0; i < 20; ++i) {
            int p = w * 20 + i;
            int j = p * 2;
            unsigned short v0, v1;
            if (j < 128) {
                int tok0 = t0 - 64 + j;
                int tok1 = tok0 + 1;
                tok0 = tok0 < 0 ? 0 : tok0;
                tok1 = tok1 < 0 ? 0 : tok1;
                v0 = Vu[(size_t)tok0 * DM + h * 64 + d];
                v1 = Vu[(size_t)tok1 * DM + h * 64 + d];
            } else {
                int n0 = j - 128;
                int c0 = cmin + n0;     if (c0 > 127) c0 = 127;
                int c1 = cmin + n0 + 1; if (c1 > 127) c1 = 127;
                v0 = CVu[(size_t)c0 * DM + h * 64 + d];
                v1 = CVu[(size_t)c1 * DM + h * 64 + d];
            }
            *(ushort2*)&Vts[d * PSTR + j] = (ushort2){v0, v1};
        }
    }

    const __hip_bfloat16* qp = Q + (size_t)(t0 + w * 16 + l16) * DM + h * 64 + quad * 8;
    short8 qf0 = *(const short8*)(qp);
    short8 qf1 = *(const short8*)(qp + 32);

    f32x4 sc[8];
#pragma unroll
    for (int jt = 0; jt < 8; ++jt) {
        int j = jt * 16 + l16;
        int tok = t0 - 64 + j;
        tok = tok < 0 ? 0 : tok;
        const __hip_bfloat16* kp = K + (size_t)tok * DM + h * 64 + quad * 8;
        short8 b0 = *(const short8*)(kp);
        short8 b1 = *(const short8*)(kp + 32);
        f32x4 a = __builtin_amdgcn_mfma_f32_16x16x32_bf16(qf0, b0, (f32x4){0.f,0.f,0.f,0.f}, 0, 0, 0);
        sc[jt]  = __builtin_amdgcn_mfma_f32_16x16x32_bf16(qf1, b1, a, 0, 0, 0);
    }
    f32x4 sc2[2];
#pragma unroll
    for (int jt = 0; jt < 2; ++jt) {
        int c = cmin + jt * 16 + l16;
        if (c > 127) c = 127;
        const __hip_bfloat16* cp = CK + (size_t)c * DM + h * 64 + quad * 8;
        short8 b0 = *(const short8*)(cp);
        short8 b1 = *(const short8*)(cp + 32);
        f32x4 a = __builtin_amdgcn_mfma_f32_16x16x32_bf16(qf0, b0, (f32x4){0.f,0.f,0.f,0.f}, 0, 0, 0);
        sc2[jt] = __builtin_amdgcn_mfma_f32_16x16x32_bf16(qf1, b1, a, 0, 0, 0);
    }

    __syncthreads();

    const int rbase = w * 16 + quad * 4;
    float gl[4], g2[4];
    float mx[4], sm[4], mx2[4], sm2[4];
#pragma unroll
    for (int reg = 0; reg < 4; ++reg) {
        int rr = rbase + reg;
        int t  = t0 + rr;
        float g = G[t * NH + h];
        int rc = (t >= 96) ? ((t - 64) >> 5) : 0;
        gl[reg] = (t > 0)  ? g        : 0.f;
        g2[reg] = (rc > 0) ? (1.f - g) : 0.f;

        int jlo = rr > (64 - t0) ? rr : (64 - t0);
        int jhi = rr + 63;
        float m = -1e30f;
#pragma unroll
        for (int jt = 0; jt < 8; ++jt) {
            int j = jt * 16 + l16;
            float s = (j >= jlo && j <= jhi) ? sc[jt][reg] * scale : -1e30f;
            sc[jt][reg] = s;
            m = fmaxf(m, s);
        }
        mx[reg] = m;

        int nvis = rc < 16 ? rc : 16;
        int clo = rc - nvis, chi = rc - 1;
        float m2 = -1e30f;
#pragma unroll
        for (int jt = 0; jt < 2; ++jt) {
            int c = cmin + jt * 16 + l16;
            float s = (c >= clo && c <= chi) ? sc2[jt][reg] * scale : -1e30f;
            sc2[jt][reg] = s;
            m2 = fmaxf(m2, s);
        }
        mx2[reg] = m2;
    }
#pragma unroll
    for (int off = 1; off <= 8; off <<= 1)
#pragma unroll
        for (int reg = 0; reg < 4; ++reg) {
            mx[reg]  = fmaxf(mx[reg],  __shfl_xor(mx[reg],  off));
            mx2[reg] = fmaxf(mx2[reg], __shfl_xor(mx2[reg], off));
        }
#pragma unroll
    for (int reg = 0; reg < 4; ++reg) {
        float s = 0.f, s2 = 0.f;
#pragma unroll
        for (int jt = 0; jt < 8; ++jt) {
            float p = __expf(sc[jt][reg] - mx[reg]);
            sc[jt][reg] = p;
            s += p;
        }
#pragma unroll
        for (int jt = 0; jt < 2; ++jt) {
            float p = __expf(sc2[jt][reg] - mx2[reg]);
            sc2[jt][reg] = p;
            s2 += p;
        }
        sm[reg] = s; sm2[reg] = s2;
    }
#pragma unroll
    for (int off = 1; off <= 8; off <<= 1)
#pragma unroll
        for (int reg = 0; reg < 4; ++reg) {
            sm[reg]  += __shfl_xor(sm[reg],  off);
            sm2[reg] += __shfl_xor(sm2[reg], off);
        }

#pragma unroll
    for (int reg = 0; reg < 4; ++reg) {
        float f1 = gl[reg] / sm[reg];
        float f2 = g2[reg] / sm2[reg];
        int rowoff = (rbase + reg) * PSTR;
#pragma unroll
        for (int jt = 0; jt < 8; ++jt) {
            __hip_bfloat16 hb = (__hip_bfloat16)(sc[jt][reg] * f1);
            Pls[rowoff + jt * 16 + l16] = *(unsigned short*)&hb;
        }
#pragma unroll
        for (int jt = 0; jt < 2; ++jt) {
            __hip_bfloat16 hb = (__hip_bfloat16)(sc2[jt][reg] * f2);
            Pls[rowoff + 128 + jt * 16 + l16] = *(unsigned short*)&hb;
        }
    }
    asm volatile("s_waitcnt lgkmcnt(0)" ::: "memory");

    f32x4 o[4];
#pragma unroll
    for (int nt = 0; nt < 4; ++nt) o[nt] = (f32x4){0.f, 0.f, 0.f, 0.f};
#pragma unroll
    for (int kt = 0; kt < 5; ++kt) {
        short8 a = *(const short8*)&Pls[(w * 16 + l16) * PSTR + kt * 32 + quad * 8];
#pragma unroll
        for (int nt = 0; nt < 4; ++nt) {
            int dd = nt * 16 + l16;
            short8 b = *(const short8*)&Vts[dd * PSTR + kt * 32 + quad * 8];
            o[nt] = __builtin_amdgcn_mfma_f32_16x16x32_bf16(a, b, o[nt], 0, 0, 0);
        }
    }

#pragma unroll
    for (int nt = 0; nt < 4; ++nt) {
#pragma unroll
        for (int reg = 0; reg < 4; ++reg) {
            int row = t0 + rbase + reg;
            int col = h * 64 + nt * 16 + l16;
            Aout[(size_t)row * DM + col] = (__hip_bfloat16)(o[nt][reg]);
        }
    }
}

extern "C" void kernel_launch(void* const* d_in, const int* in_sizes, int n_in,
                              void* d_out, int out_size, void* d_ws, size_t ws_size,
                              hipStream_t stream)
{
    const float* x  = (const float*)d_in[0];
    const float* Wq = (const float*)d_in[1];
    const float* bq = (const float*)d_in[2];
    const float* Wk = (const float*)d_in[3];
    const float* bk = (const float*)d_in[4];
    const float* Wv = (const float*)d_in[5];
    const float* bv = (const float*)d_in[6];
    const float* Wo = (const float*)d_in[7];
    const float* bo = (const float*)d_in[8];
    const float* Wg = (const float*)d_in[9];
    const float* bg = (const float*)d_in[10];
    float* out = (float*)d_out;

    char* ws = (char*)d_ws;
    const size_t MB = 1024 * 1024;
    __hip_bfloat16* xb  = (__hip_bfloat16*)(ws + 0 * MB);   // 8 MB
    __hip_bfloat16* Qb  = (__hip_bfloat16*)(ws + 8 * MB);   // 8 MB
    __hip_bfloat16* Kb  = (__hip_bfloat16*)(ws + 16 * MB);  // 8 MB
    __hip_bfloat16* Vb  = (__hip_bfloat16*)(ws + 24 * MB);  // 8 MB
    __hip_bfloat16* Ab  = (__hip_bfloat16*)(ws + 32 * MB);  // 8 MB
    __hip_bfloat16* Wqb = (__hip_bfloat16*)(ws + 40 * MB);  // 2 MB
    __hip_bfloat16* Wkb = (__hip_bfloat16*)(ws + 42 * MB);  // 2 MB
    __hip_bfloat16* Wvb = (__hip_bfloat16*)(ws + 44 * MB);  // 2 MB
    __hip_bfloat16* Wob = (__hip_bfloat16*)(ws + 46 * MB);  // 2 MB
    __hip_bfloat16* CKb = (__hip_bfloat16*)(ws + 48 * MB);            // 256 KB
    __hip_bfloat16* CVb = (__hip_bfloat16*)(ws + 48 * MB + 256*1024); // 256 KB
    float* Gf           = (float*)(ws + 48 * MB + 512 * 1024);        // 256 KB

    cast_all<<<dim3(8192), 256, 0, stream>>>(x, Wq, Wk, Wv, Wo, xb, Wqb, Wkb, Wvb, Wob);

    // Fused QKV GEMM: grid (32, 24); group = blockIdx.y>>3.
    gemm128<__hip_bfloat16><<<dim3(32, 24), 256, 0, stream>>>(
        xb, Wqb, Wkb, Wvb, bq, bk, bv, Qb, Kb, Vb);
    g_kernel<<<dim3(TT), 64, 0, stream>>>(x, Wg, bg, Gf);
    chunk_kernel<<<dim3(128, 4), 256, 0, stream>>>(Kb, Vb, CKb, CVb);
    attn_mfma<<<dim3(64, 16), 256, 0, stream>>>(Qb, Kb, Vb, CKb, CVb, Gf, Ab);
    // Output GEMM: grid (32, 8) -> group 0 only.
    gemm128<float><<<dim3(32, 8), 256, 0, stream>>>(
        Ab, Wob, Wob, Wob, bo, bo, bo, out, out, out);
}

// Round 6
// 183.096 us; speedup vs baseline: 3.3938x; 1.0622x over previous
//
#include <hip/hip_runtime.h>
#include <hip/hip_bf16.h>
#include <math.h>

typedef __attribute__((ext_vector_type(8))) short short8;
typedef __attribute__((ext_vector_type(4))) float f32x4;

#define TT 4096
#define DM 1024
#define NH 16
#define HD 64
#define PSTR 168   // attn LDS row stride in halfwords

typedef __attribute__((address_space(3))) unsigned int lds_u32;
typedef __attribute__((address_space(1))) unsigned int glb_u32;

__device__ __forceinline__ void async_cp16(const void* g, void* l) {
    __builtin_amdgcn_global_load_lds((glb_u32*)g, (lds_u32*)l, 16, 0, 0);
}

// Fused fp32 -> bf16 cast for x + Wq/Wk/Wv/Wo + Wg.
__global__ __launch_bounds__(256) void cast_all(
    const float* __restrict__ x,  const float* __restrict__ wq,
    const float* __restrict__ wk, const float* __restrict__ wv,
    const float* __restrict__ wo, const float* __restrict__ wg,
    __hip_bfloat16* __restrict__ xb,  __hip_bfloat16* __restrict__ wqb,
    __hip_bfloat16* __restrict__ wkb, __hip_bfloat16* __restrict__ wvb,
    __hip_bfloat16* __restrict__ wob, __hip_bfloat16* __restrict__ wgb)
{
    int b = blockIdx.x;
    const float* src;
    __hip_bfloat16* dst;
    size_t base;
    if (b < 4096)      { src = x;  dst = xb;  base = (size_t)b * 1024; }
    else if (b < 5120) { src = wq; dst = wqb; base = (size_t)(b - 4096) * 1024; }
    else if (b < 6144) { src = wk; dst = wkb; base = (size_t)(b - 5120) * 1024; }
    else if (b < 7168) { src = wv; dst = wvb; base = (size_t)(b - 6144) * 1024; }
    else if (b < 8192) { src = wo; dst = wob; base = (size_t)(b - 7168) * 1024; }
    else               { src = wg; dst = wgb; base = (size_t)(b - 8192) * 1024; }
    size_t i = base + (size_t)threadIdx.x * 4;
    float4 v = *(const float4*)(src + i);
    __hip_bfloat16 h0 = (__hip_bfloat16)v.x;
    __hip_bfloat16 h1 = (__hip_bfloat16)v.y;
    __hip_bfloat16 h2 = (__hip_bfloat16)v.z;
    __hip_bfloat16 h3 = (__hip_bfloat16)v.w;
    ushort4 u;
    u.x = *(unsigned short*)&h0;
    u.y = *(unsigned short*)&h1;
    u.z = *(unsigned short*)&h2;
    u.w = *(unsigned short*)&h3;
    *(ushort4*)((unsigned short*)dst + i) = u;
}

// 128x128-tile GEMM with 2-stage LDS double buffer.
// Grid (M/128, 8*ngroups): group = blockIdx.y>>3 selects B/bias/O (QKV fusion).
template <typename OutT>
__global__ __launch_bounds__(256) void gemm128(
    const __hip_bfloat16* __restrict__ A,
    const __hip_bfloat16* __restrict__ B0, const __hip_bfloat16* __restrict__ B1,
    const __hip_bfloat16* __restrict__ B2,
    const float* __restrict__ c0, const float* __restrict__ c1, const float* __restrict__ c2,
    OutT* __restrict__ O0, OutT* __restrict__ O1, OutT* __restrict__ O2)
{
    const int K = DM;
    __shared__ __align__(16) unsigned short sA[2][128 * 32];
    __shared__ __align__(16) unsigned short sB[2][128 * 32];

    const int grp = blockIdx.y >> 3;
    const __hip_bfloat16* B = grp == 0 ? B0 : (grp == 1 ? B1 : B2);
    const float* bias       = grp == 0 ? c0 : (grp == 1 ? c1 : c2);
    OutT* O                 = grp == 0 ? O0 : (grp == 1 ? O1 : O2);

    const int tid  = threadIdx.x;
    const int w    = tid >> 6;
    const int lane = tid & 63;
    const int l16  = lane & 15;
    const int quad = lane >> 4;
    const int rowBase = blockIdx.x * 128;
    const int colBase = (blockIdx.y & 7) * 128;

    // staging map: lane -> (srow = lane>>2, slot = lane&3); fetch global chunk slot^s(srow)
    const int srow   = lane >> 2;
    const int sswz   = (srow & 3) ^ (srow >> 2);
    const int gchunk = (lane & 3) ^ sswz;
    const __hip_bfloat16* gA = A + (size_t)(rowBase + w * 32 + srow) * K + gchunk * 8;
    const __hip_bfloat16* gB = B + (size_t)(colBase + w * 32 + srow) * K + gchunk * 8;
    const int loff = w * 32 * 32;

    // fragment read swizzle (row = base16 + l16 -> s depends only on l16)
    const int fswz = (l16 & 3) ^ (l16 >> 2);
    const int mrow = (w & 1) * 64;
    const int ncol = (w >> 1) * 64;

    f32x4 acc[4][4];
#pragma unroll
    for (int i = 0; i < 4; ++i)
#pragma unroll
        for (int j = 0; j < 4; ++j) acc[i][j] = (f32x4){0.f, 0.f, 0.f, 0.f};

    // prologue: stage k0=0 into buffer 0
    async_cp16(gA, sA[0] + loff);
    async_cp16(gA + (size_t)16 * K, sA[0] + loff + 16 * 32);
    async_cp16(gB, sB[0] + loff);
    async_cp16(gB + (size_t)16 * K, sB[0] + loff + 16 * 32);

    for (int k0 = 0; k0 < K; k0 += 32) {
        const int cur = (k0 >> 5) & 1;
        __syncthreads();   // drains this wave's cps -> buffer cur ready for all
        if (k0 + 32 < K) {
            const int nxt = cur ^ 1;
            async_cp16(gA + k0 + 32, sA[nxt] + loff);
            async_cp16(gA + k0 + 32 + (size_t)16 * K, sA[nxt] + loff + 16 * 32);
            async_cp16(gB + k0 + 32, sB[nxt] + loff);
            async_cp16(gB + k0 + 32 + (size_t)16 * K, sB[nxt] + loff + 16 * 32);
        }

        short8 af[4], bf[4];
#pragma unroll
        for (int mt = 0; mt < 4; ++mt)
            af[mt] = *(const short8*)&sA[cur][(mrow + mt * 16 + l16) * 32 + (quad ^ fswz) * 8];
#pragma unroll
        for (int nt = 0; nt < 4; ++nt)
            bf[nt] = *(const short8*)&sB[cur][(ncol + nt * 16 + l16) * 32 + (quad ^ fswz) * 8];
#pragma unroll
        for (int mt = 0; mt < 4; ++mt)
#pragma unroll
            for (int nt = 0; nt < 4; ++nt)
                acc[mt][nt] = __builtin_amdgcn_mfma_f32_16x16x32_bf16(af[mt], bf[nt], acc[mt][nt], 0, 0, 0);
    }

#pragma unroll
    for (int nt = 0; nt < 4; ++nt) {
        int col = colBase + ncol + nt * 16 + l16;
        float bv = bias[col];
#pragma unroll
        for (int mt = 0; mt < 4; ++mt) {
#pragma unroll
            for (int r = 0; r < 4; ++r) {
                int row = rowBase + mrow + mt * 16 + quad * 4 + r;
                O[(size_t)row * DM + col] = (OutT)(acc[mt][nt][r] + bv);
            }
        }
    }
}

// Gate GEMM via MFMA: G[t,h] = sigmoid(xb[t,:] . Wgb[h,:] + bg[h]).
// One wave per 16-token tile; C layout: col=head(l16), row=quad*4+reg.
__global__ __launch_bounds__(64) void g_mfma(
    const __hip_bfloat16* __restrict__ xb,
    const __hip_bfloat16* __restrict__ Wgb,
    const float* __restrict__ bg,
    float* __restrict__ G)
{
    const int lane = threadIdx.x;
    const int l16  = lane & 15;
    const int quad = lane >> 4;
    const int t0   = blockIdx.x * 16;
    const __hip_bfloat16* ap = xb + (size_t)(t0 + l16) * DM + quad * 8;
    const __hip_bfloat16* bp = Wgb + (size_t)l16 * DM + quad * 8;
    f32x4 acc = (f32x4){0.f, 0.f, 0.f, 0.f};
#pragma unroll 4
    for (int k0 = 0; k0 < DM; k0 += 32) {
        short8 a = *(const short8*)(ap + k0);
        short8 b = *(const short8*)(bp + k0);
        acc = __builtin_amdgcn_mfma_f32_16x16x32_bf16(a, b, acc, 0, 0, 0);
    }
    float bgv = bg[l16];
#pragma unroll
    for (int r = 0; r < 4; ++r) {
        int t = t0 + quad * 4 + r;
        float z = acc[r] + bgv;
        G[t * NH + l16] = 1.f / (1.f + __expf(-z));
    }
}

// Chunk means over 32 consecutive tokens: CK[c,:], CV[c,:], c = 0..127.
__global__ __launch_bounds__(256) void chunk_kernel(
    const __hip_bfloat16* __restrict__ K,
    const __hip_bfloat16* __restrict__ V,
    __hip_bfloat16* __restrict__ CK,
    __hip_bfloat16* __restrict__ CV)
{
    const int c = blockIdx.x;
    const int d = blockIdx.y * 256 + threadIdx.x;
    float ak = 0.f, av = 0.f;
    for (int i = 0; i < 32; ++i) {
        ak += (float)K[(size_t)(c * 32 + i) * DM + d];
        av += (float)V[(size_t)(c * 32 + i) * DM + d];
    }
    CK[(size_t)c * DM + d] = (__hip_bfloat16)(ak * (1.f / 32.f));
    CV[(size_t)c * DM + d] = (__hip_bfloat16)(av * (1.f / 32.f));
}

// MFMA attention: 64 queries x 1 head per block (grid 64 x 16, 256 threads).
__global__ __launch_bounds__(256) void attn_mfma(
    const __hip_bfloat16* __restrict__ Q,
    const __hip_bfloat16* __restrict__ K,
    const __hip_bfloat16* __restrict__ V,
    const __hip_bfloat16* __restrict__ CK,
    const __hip_bfloat16* __restrict__ CV,
    const float* __restrict__ G,
    __hip_bfloat16* __restrict__ Aout)
{
    __shared__ alignas(16) unsigned short Pls[64 * PSTR];
    __shared__ alignas(16) unsigned short Vts[64 * PSTR];

    const int h   = blockIdx.y;
    const int t0  = blockIdx.x * 64;
    const int tid = threadIdx.x;
    const int w    = tid >> 6;
    const int lane = tid & 63;
    const int l16  = lane & 15;
    const int quad = lane >> 4;
    const float scale = 0.125f;

    const int rc0  = (t0 >= 96) ? ((t0 - 64) >> 5) : 0;
    const int cmin = rc0 > 16 ? rc0 - 16 : 0;

    const unsigned short* Vu  = (const unsigned short*)V;
    const unsigned short* CVu = (const unsigned short*)CV;

    {
        const int d = lane;
#pragma unroll
        for (int i = 0; i < 20; ++i) {
            int p = w * 20 + i;
            int j = p * 2;
            unsigned short v0, v1;
            if (j < 128) {
                int tok0 = t0 - 64 + j;
                int tok1 = tok0 + 1;
                tok0 = tok0 < 0 ? 0 : tok0;
                tok1 = tok1 < 0 ? 0 : tok1;
                v0 = Vu[(size_t)tok0 * DM + h * 64 + d];
                v1 = Vu[(size_t)tok1 * DM + h * 64 + d];
            } else {
                int n0 = j - 128;
                int c0 = cmin + n0;     if (c0 > 127) c0 = 127;
                int c1 = cmin + n0 + 1; if (c1 > 127) c1 = 127;
                v0 = CVu[(size_t)c0 * DM + h * 64 + d];
                v1 = CVu[(size_t)c1 * DM + h * 64 + d];
            }
            *(ushort2*)&Vts[d * PSTR + j] = (ushort2){v0, v1};
        }
    }

    const __hip_bfloat16* qp = Q + (size_t)(t0 + w * 16 + l16) * DM + h * 64 + quad * 8;
    short8 qf0 = *(const short8*)(qp);
    short8 qf1 = *(const short8*)(qp + 32);

    f32x4 sc[8];
#pragma unroll
    for (int jt = 0; jt < 8; ++jt) {
        int j = jt * 16 + l16;
        int tok = t0 - 64 + j;
        tok = tok < 0 ? 0 : tok;
        const __hip_bfloat16* kp = K + (size_t)tok * DM + h * 64 + quad * 8;
        short8 b0 = *(const short8*)(kp);
        short8 b1 = *(const short8*)(kp + 32);
        f32x4 a = __builtin_amdgcn_mfma_f32_16x16x32_bf16(qf0, b0, (f32x4){0.f,0.f,0.f,0.f}, 0, 0, 0);
        sc[jt]  = __builtin_amdgcn_mfma_f32_16x16x32_bf16(qf1, b1, a, 0, 0, 0);
    }
    f32x4 sc2[2];
#pragma unroll
    for (int jt = 0; jt < 2; ++jt) {
        int c = cmin + jt * 16 + l16;
        if (c > 127) c = 127;
        const __hip_bfloat16* cp = CK + (size_t)c * DM + h * 64 + quad * 8;
        short8 b0 = *(const short8*)(cp);
        short8 b1 = *(const short8*)(cp + 32);
        f32x4 a = __builtin_amdgcn_mfma_f32_16x16x32_bf16(qf0, b0, (f32x4){0.f,0.f,0.f,0.f}, 0, 0, 0);
        sc2[jt] = __builtin_amdgcn_mfma_f32_16x16x32_bf16(qf1, b1, a, 0, 0, 0);
    }

    __syncthreads();

    const int rbase = w * 16 + quad * 4;
    float gl[4], g2[4];
    float mx[4], sm[4], mx2[4], sm2[4];
#pragma unroll
    for (int reg = 0; reg < 4; ++reg) {
        int rr = rbase + reg;
        int t  = t0 + rr;
        float g = G[t * NH + h];
        int rc = (t >= 96) ? ((t - 64) >> 5) : 0;
        gl[reg] = (t > 0)  ? g        : 0.f;
        g2[reg] = (rc > 0) ? (1.f - g) : 0.f;

        int jlo = rr > (64 - t0) ? rr : (64 - t0);
        int jhi = rr + 63;
        float m = -1e30f;
#pragma unroll
        for (int jt = 0; jt < 8; ++jt) {
            int j = jt * 16 + l16;
            float s = (j >= jlo && j <= jhi) ? sc[jt][reg] * scale : -1e30f;
            sc[jt][reg] = s;
            m = fmaxf(m, s);
        }
        mx[reg] = m;

        int nvis = rc < 16 ? rc : 16;
        int clo = rc - nvis, chi = rc - 1;
        float m2 = -1e30f;
#pragma unroll
        for (int jt = 0; jt < 2; ++jt) {
            int c = cmin + jt * 16 + l16;
            float s = (c >= clo && c <= chi) ? sc2[jt][reg] * scale : -1e30f;
            sc2[jt][reg] = s;
            m2 = fmaxf(m2, s);
        }
        mx2[reg] = m2;
    }
#pragma unroll
    for (int off = 1; off <= 8; off <<= 1)
#pragma unroll
        for (int reg = 0; reg < 4; ++reg) {
            mx[reg]  = fmaxf(mx[reg],  __shfl_xor(mx[reg],  off));
            mx2[reg] = fmaxf(mx2[reg], __shfl_xor(mx2[reg], off));
        }
#pragma unroll
    for (int reg = 0; reg < 4; ++reg) {
        float s = 0.f, s2 = 0.f;
#pragma unroll
        for (int jt = 0; jt < 8; ++jt) {
            float p = __expf(sc[jt][reg] - mx[reg]);
            sc[jt][reg] = p;
            s += p;
        }
#pragma unroll
        for (int jt = 0; jt < 2; ++jt) {
            float p = __expf(sc2[jt][reg] - mx2[reg]);
            sc2[jt][reg] = p;
            s2 += p;
        }
        sm[reg] = s; sm2[reg] = s2;
    }
#pragma unroll
    for (int off = 1; off <= 8; off <<= 1)
#pragma unroll
        for (int reg = 0; reg < 4; ++reg) {
            sm[reg]  += __shfl_xor(sm[reg],  off);
            sm2[reg] += __shfl_xor(sm2[reg], off);
        }

#pragma unroll
    for (int reg = 0; reg < 4; ++reg) {
        float f1 = gl[reg] / sm[reg];
        float f2 = g2[reg] / sm2[reg];
        int rowoff = (rbase + reg) * PSTR;
#pragma unroll
        for (int jt = 0; jt < 8; ++jt) {
            __hip_bfloat16 hb = (__hip_bfloat16)(sc[jt][reg] * f1);
            Pls[rowoff + jt * 16 + l16] = *(unsigned short*)&hb;
        }
#pragma unroll
        for (int jt = 0; jt < 2; ++jt) {
            __hip_bfloat16 hb = (__hip_bfloat16)(sc2[jt][reg] * f2);
            Pls[rowoff + 128 + jt * 16 + l16] = *(unsigned short*)&hb;
        }
    }
    asm volatile("s_waitcnt lgkmcnt(0)" ::: "memory");

    f32x4 o[4];
#pragma unroll
    for (int nt = 0; nt < 4; ++nt) o[nt] = (f32x4){0.f, 0.f, 0.f, 0.f};
#pragma unroll
    for (int kt = 0; kt < 5; ++kt) {
        short8 a = *(const short8*)&Pls[(w * 16 + l16) * PSTR + kt * 32 + quad * 8];
#pragma unroll
        for (int nt = 0; nt < 4; ++nt) {
            int dd = nt * 16 + l16;
            short8 b = *(const short8*)&Vts[dd * PSTR + kt * 32 + quad * 8];
            o[nt] = __builtin_amdgcn_mfma_f32_16x16x32_bf16(a, b, o[nt], 0, 0, 0);
        }
    }

#pragma unroll
    for (int nt = 0; nt < 4; ++nt) {
#pragma unroll
        for (int reg = 0; reg < 4; ++reg) {
            int row = t0 + rbase + reg;
            int col = h * 64 + nt * 16 + l16;
            Aout[(size_t)row * DM + col] = (__hip_bfloat16)(o[nt][reg]);
        }
    }
}

extern "C" void kernel_launch(void* const* d_in, const int* in_sizes, int n_in,
                              void* d_out, int out_size, void* d_ws, size_t ws_size,
                              hipStream_t stream)
{
    const float* x  = (const float*)d_in[0];
    const float* Wq = (const float*)d_in[1];
    const float* bq = (const float*)d_in[2];
    const float* Wk = (const float*)d_in[3];
    const float* bk = (const float*)d_in[4];
    const float* Wv = (const float*)d_in[5];
    const float* bv = (const float*)d_in[6];
    const float* Wo = (const float*)d_in[7];
    const float* bo = (const float*)d_in[8];
    const float* Wg = (const float*)d_in[9];
    const float* bg = (const float*)d_in[10];
    float* out = (float*)d_out;

    char* ws = (char*)d_ws;
    const size_t MB = 1024 * 1024;
    __hip_bfloat16* xb  = (__hip_bfloat16*)(ws + 0 * MB);   // 8 MB
    __hip_bfloat16* Qb  = (__hip_bfloat16*)(ws + 8 * MB);   // 8 MB
    __hip_bfloat16* Kb  = (__hip_bfloat16*)(ws + 16 * MB);  // 8 MB
    __hip_bfloat16* Vb  = (__hip_bfloat16*)(ws + 24 * MB);  // 8 MB
    __hip_bfloat16* Ab  = (__hip_bfloat16*)(ws + 32 * MB);  // 8 MB
    __hip_bfloat16* Wqb = (__hip_bfloat16*)(ws + 40 * MB);  // 2 MB
    __hip_bfloat16* Wkb = (__hip_bfloat16*)(ws + 42 * MB);  // 2 MB
    __hip_bfloat16* Wvb = (__hip_bfloat16*)(ws + 44 * MB);  // 2 MB
    __hip_bfloat16* Wob = (__hip_bfloat16*)(ws + 46 * MB);  // 2 MB
    __hip_bfloat16* CKb = (__hip_bfloat16*)(ws + 48 * MB);            // 256 KB
    __hip_bfloat16* CVb = (__hip_bfloat16*)(ws + 48 * MB + 256*1024); // 256 KB
    float* Gf           = (float*)(ws + 48 * MB + 512 * 1024);        // 256 KB
    __hip_bfloat16* Wgb = (__hip_bfloat16*)(ws + 48 * MB + 768*1024); // 32 KB

    cast_all<<<dim3(8208), 256, 0, stream>>>(x, Wq, Wk, Wv, Wo, Wg,
                                             xb, Wqb, Wkb, Wvb, Wob, Wgb);

    // Fused QKV GEMM: grid (32, 24); group = blockIdx.y>>3.
    gemm128<__hip_bfloat16><<<dim3(32, 24), 256, 0, stream>>>(
        xb, Wqb, Wkb, Wvb, bq, bk, bv, Qb, Kb, Vb);
    g_mfma<<<dim3(256), 64, 0, stream>>>(xb, Wgb, bg, Gf);
    chunk_kernel<<<dim3(128, 4), 256, 0, stream>>>(Kb, Vb, CKb, CVb);
    attn_mfma<<<dim3(64, 16), 256, 0, stream>>>(Qb, Kb, Vb, CKb, CVb, Gf, Ab);
    // Output GEMM: grid (32, 8) -> group 0 only.
    gemm128<float><<<dim3(32, 8), 256, 0, stream>>>(
        Ab, Wob, Wob, Wob, bo, bo, bo, out, out, out);
}

// Round 7
// 176.277 us; speedup vs baseline: 3.5251x; 1.0387x over previous
//
#include <hip/hip_runtime.h>
#include <hip/hip_bf16.h>
#include <math.h>

typedef __attribute__((ext_vector_type(8))) short short8;
typedef __attribute__((ext_vector_type(4))) float f32x4;

#define TT 4096
#define DM 1024
#define NH 16
#define HD 64
#define PSTR 168   // attn LDS row stride in halfwords (84 dwords == 20 mod 32 banks)

typedef __attribute__((address_space(3))) unsigned int lds_u32;
typedef __attribute__((address_space(1))) unsigned int glb_u32;

__device__ __forceinline__ void async_cp16(const void* g, void* l) {
    __builtin_amdgcn_global_load_lds((glb_u32*)g, (lds_u32*)l, 16, 0, 0);
}

// Fused fp32 -> bf16 cast for x + Wq/Wk/Wv/Wo + Wg.
__global__ __launch_bounds__(256) void cast_all(
    const float* __restrict__ x,  const float* __restrict__ wq,
    const float* __restrict__ wk, const float* __restrict__ wv,
    const float* __restrict__ wo, const float* __restrict__ wg,
    __hip_bfloat16* __restrict__ xb,  __hip_bfloat16* __restrict__ wqb,
    __hip_bfloat16* __restrict__ wkb, __hip_bfloat16* __restrict__ wvb,
    __hip_bfloat16* __restrict__ wob, __hip_bfloat16* __restrict__ wgb)
{
    int b = blockIdx.x;
    const float* src;
    __hip_bfloat16* dst;
    size_t base;
    if (b < 4096)      { src = x;  dst = xb;  base = (size_t)b * 1024; }
    else if (b < 5120) { src = wq; dst = wqb; base = (size_t)(b - 4096) * 1024; }
    else if (b < 6144) { src = wk; dst = wkb; base = (size_t)(b - 5120) * 1024; }
    else if (b < 7168) { src = wv; dst = wvb; base = (size_t)(b - 6144) * 1024; }
    else if (b < 8192) { src = wo; dst = wob; base = (size_t)(b - 7168) * 1024; }
    else               { src = wg; dst = wgb; base = (size_t)(b - 8192) * 1024; }
    size_t i = base + (size_t)threadIdx.x * 4;
    float4 v = *(const float4*)(src + i);
    __hip_bfloat16 h0 = (__hip_bfloat16)v.x;
    __hip_bfloat16 h1 = (__hip_bfloat16)v.y;
    __hip_bfloat16 h2 = (__hip_bfloat16)v.z;
    __hip_bfloat16 h3 = (__hip_bfloat16)v.w;
    ushort4 u;
    u.x = *(unsigned short*)&h0;
    u.y = *(unsigned short*)&h1;
    u.z = *(unsigned short*)&h2;
    u.w = *(unsigned short*)&h3;
    *(ushort4*)((unsigned short*)dst + i) = u;
}

// 128x128-tile GEMM, single-buffered (32 KB LDS keeps 4+ blocks/CU; dbuf at
// 64 KB drops to 2 blocks/CU and regresses ~15 us -- measured round 6).
// Grid (M/128, 8*ngroups): group = blockIdx.y>>3 selects B/bias/O (QKV fusion).
template <typename OutT>
__global__ __launch_bounds__(256) void gemm128(
    const __hip_bfloat16* __restrict__ A,
    const __hip_bfloat16* __restrict__ B0, const __hip_bfloat16* __restrict__ B1,
    const __hip_bfloat16* __restrict__ B2,
    const float* __restrict__ c0, const float* __restrict__ c1, const float* __restrict__ c2,
    OutT* __restrict__ O0, OutT* __restrict__ O1, OutT* __restrict__ O2)
{
    const int K = DM;
    __shared__ __align__(16) unsigned short sA[128 * 32];
    __shared__ __align__(16) unsigned short sB[128 * 32];

    const int grp = blockIdx.y >> 3;
    const __hip_bfloat16* B = grp == 0 ? B0 : (grp == 1 ? B1 : B2);
    const float* bias       = grp == 0 ? c0 : (grp == 1 ? c1 : c2);
    OutT* O                 = grp == 0 ? O0 : (grp == 1 ? O1 : O2);

    const int tid  = threadIdx.x;
    const int w    = tid >> 6;
    const int lane = tid & 63;
    const int l16  = lane & 15;
    const int quad = lane >> 4;
    const int rowBase = blockIdx.x * 128;
    const int colBase = (blockIdx.y & 7) * 128;

    const int srow   = lane >> 2;
    const int sswz   = (srow & 3) ^ (srow >> 2);
    const int gchunk = (lane & 3) ^ sswz;
    const __hip_bfloat16* gA = A + (size_t)(rowBase + w * 32 + srow) * K + gchunk * 8;
    const __hip_bfloat16* gB = B + (size_t)(colBase + w * 32 + srow) * K + gchunk * 8;
    unsigned short* lA = sA + w * 32 * 32;
    unsigned short* lB = sB + w * 32 * 32;

    const int fswz = (l16 & 3) ^ (l16 >> 2);
    const int mrow = (w & 1) * 64;
    const int ncol = (w >> 1) * 64;

    f32x4 acc[4][4];
#pragma unroll
    for (int i = 0; i < 4; ++i)
#pragma unroll
        for (int j = 0; j < 4; ++j) acc[i][j] = (f32x4){0.f, 0.f, 0.f, 0.f};

    for (int k0 = 0; k0 < K; k0 += 32) {
        __syncthreads();
        async_cp16(gA + k0, lA);
        async_cp16(gA + k0 + (size_t)16 * K, lA + 16 * 32);
        async_cp16(gB + k0, lB);
        async_cp16(gB + k0 + (size_t)16 * K, lB + 16 * 32);
        __syncthreads();

        short8 af[4], bf[4];
#pragma unroll
        for (int mt = 0; mt < 4; ++mt)
            af[mt] = *(const short8*)&sA[(mrow + mt * 16 + l16) * 32 + (quad ^ fswz) * 8];
#pragma unroll
        for (int nt = 0; nt < 4; ++nt)
            bf[nt] = *(const short8*)&sB[(ncol + nt * 16 + l16) * 32 + (quad ^ fswz) * 8];
#pragma unroll
        for (int mt = 0; mt < 4; ++mt)
#pragma unroll
            for (int nt = 0; nt < 4; ++nt)
                acc[mt][nt] = __builtin_amdgcn_mfma_f32_16x16x32_bf16(af[mt], bf[nt], acc[mt][nt], 0, 0, 0);
    }

#pragma unroll
    for (int nt = 0; nt < 4; ++nt) {
        int col = colBase + ncol + nt * 16 + l16;
        float bv = bias[col];
#pragma unroll
        for (int mt = 0; mt < 4; ++mt) {
#pragma unroll
            for (int r = 0; r < 4; ++r) {
                int row = rowBase + mrow + mt * 16 + quad * 4 + r;
                O[(size_t)row * DM + col] = (OutT)(acc[mt][nt][r] + bv);
            }
        }
    }
}

// 128x64-tile GEMM for the Wo projection: 12 KB LDS, grid (32,16) = 512
// blocks = 2+/CU (the 128x128 version gave only 1 block/CU at N=1024).
template <typename OutT>
__global__ __launch_bounds__(256) void gemm_n64(
    const __hip_bfloat16* __restrict__ A,
    const __hip_bfloat16* __restrict__ B,
    const float* __restrict__ bias,
    OutT* __restrict__ O)
{
    const int K = DM;
    __shared__ __align__(16) unsigned short sA[128 * 32];
    __shared__ __align__(16) unsigned short sB[64 * 32];

    const int tid  = threadIdx.x;
    const int w    = tid >> 6;
    const int lane = tid & 63;
    const int l16  = lane & 15;
    const int quad = lane >> 4;
    const int rowBase = blockIdx.x * 128;
    const int colBase = blockIdx.y * 64;

    const int srow   = lane >> 2;
    const int sswz   = (srow & 3) ^ (srow >> 2);
    const int gchunk = (lane & 3) ^ sswz;
    const __hip_bfloat16* gA = A + (size_t)(rowBase + w * 32 + srow) * K + gchunk * 8;
    const __hip_bfloat16* gB = B + (size_t)(colBase + w * 16 + srow) * K + gchunk * 8;
    unsigned short* lA = sA + w * 32 * 32;
    unsigned short* lB = sB + w * 16 * 32;

    const int fswz = (l16 & 3) ^ (l16 >> 2);
    const int mrow = w * 32;

    f32x4 acc[2][4];
#pragma unroll
    for (int i = 0; i < 2; ++i)
#pragma unroll
        for (int j = 0; j < 4; ++j) acc[i][j] = (f32x4){0.f, 0.f, 0.f, 0.f};

    for (int k0 = 0; k0 < K; k0 += 32) {
        __syncthreads();
        async_cp16(gA + k0, lA);
        async_cp16(gA + k0 + (size_t)16 * K, lA + 16 * 32);
        async_cp16(gB + k0, lB);
        __syncthreads();

        short8 af[2], bf[4];
#pragma unroll
        for (int mt = 0; mt < 2; ++mt)
            af[mt] = *(const short8*)&sA[(mrow + mt * 16 + l16) * 32 + (quad ^ fswz) * 8];
#pragma unroll
        for (int nt = 0; nt < 4; ++nt)
            bf[nt] = *(const short8*)&sB[(nt * 16 + l16) * 32 + (quad ^ fswz) * 8];
#pragma unroll
        for (int mt = 0; mt < 2; ++mt)
#pragma unroll
            for (int nt = 0; nt < 4; ++nt)
                acc[mt][nt] = __builtin_amdgcn_mfma_f32_16x16x32_bf16(af[mt], bf[nt], acc[mt][nt], 0, 0, 0);
    }

#pragma unroll
    for (int nt = 0; nt < 4; ++nt) {
        int col = colBase + nt * 16 + l16;
        float bv = bias[col];
#pragma unroll
        for (int mt = 0; mt < 2; ++mt) {
#pragma unroll
            for (int r = 0; r < 4; ++r) {
                int row = rowBase + mrow + mt * 16 + quad * 4 + r;
                O[(size_t)row * DM + col] = (OutT)(acc[mt][nt][r] + bv);
            }
        }
    }
}

// Gate GEMM via MFMA: G[t,h] = sigmoid(xb[t,:] . Wgb[h,:] + bg[h]).
__global__ __launch_bounds__(64) void g_mfma(
    const __hip_bfloat16* __restrict__ xb,
    const __hip_bfloat16* __restrict__ Wgb,
    const float* __restrict__ bg,
    float* __restrict__ G)
{
    const int lane = threadIdx.x;
    const int l16  = lane & 15;
    const int quad = lane >> 4;
    const int t0   = blockIdx.x * 16;
    const __hip_bfloat16* ap = xb + (size_t)(t0 + l16) * DM + quad * 8;
    const __hip_bfloat16* bp = Wgb + (size_t)l16 * DM + quad * 8;
    f32x4 acc = (f32x4){0.f, 0.f, 0.f, 0.f};
#pragma unroll 4
    for (int k0 = 0; k0 < DM; k0 += 32) {
        short8 a = *(const short8*)(ap + k0);
        short8 b = *(const short8*)(bp + k0);
        acc = __builtin_amdgcn_mfma_f32_16x16x32_bf16(a, b, acc, 0, 0, 0);
    }
    float bgv = bg[l16];
#pragma unroll
    for (int r = 0; r < 4; ++r) {
        int t = t0 + quad * 4 + r;
        float z = acc[r] + bgv;
        G[t * NH + l16] = 1.f / (1.f + __expf(-z));
    }
}

// Chunk means over 32 consecutive tokens: CK[c,:], CV[c,:], c = 0..127.
__global__ __launch_bounds__(256) void chunk_kernel(
    const __hip_bfloat16* __restrict__ K,
    const __hip_bfloat16* __restrict__ V,
    __hip_bfloat16* __restrict__ CK,
    __hip_bfloat16* __restrict__ CV)
{
    const int c = blockIdx.x;
    const int d = blockIdx.y * 256 + threadIdx.x;
    float ak = 0.f, av = 0.f;
    for (int i = 0; i < 32; ++i) {
        ak += (float)K[(size_t)(c * 32 + i) * DM + d];
        av += (float)V[(size_t)(c * 32 + i) * DM + d];
    }
    CK[(size_t)c * DM + d] = (__hip_bfloat16)(ak * (1.f / 32.f));
    CV[(size_t)c * DM + d] = (__hip_bfloat16)(av * (1.f / 32.f));
}

// MFMA attention: 64 queries x 1 head per block (grid 64 x 16, 256 threads).
__global__ __launch_bounds__(256) void attn_mfma(
    const __hip_bfloat16* __restrict__ Q,
    const __hip_bfloat16* __restrict__ K,
    const __hip_bfloat16* __restrict__ V,
    const __hip_bfloat16* __restrict__ CK,
    const __hip_bfloat16* __restrict__ CV,
    const float* __restrict__ G,
    __hip_bfloat16* __restrict__ Aout)
{
    __shared__ alignas(16) unsigned short Pls[64 * PSTR];
    __shared__ alignas(16) unsigned short Vts[64 * PSTR];

    const int h   = blockIdx.y;
    const int t0  = blockIdx.x * 64;
    const int tid = threadIdx.x;
    const int w    = tid >> 6;
    const int lane = tid & 63;
    const int l16  = lane & 15;
    const int quad = lane >> 4;
    const float scale = 0.125f;

    const int rc0  = (t0 >= 96) ? ((t0 - 64) >> 5) : 0;
    const int cmin = rc0 > 16 ? rc0 - 16 : 0;

    const unsigned short* Vu  = (const unsigned short*)V;
    const unsigned short* CVu = (const unsigned short*)CV;

    // ---- stage V^T (+ CV^T) into LDS via 16B row-chunk loads + packed writes.
    // Wave w owns dim-groups g = 2w, 2w+1; lane owns slot-pair (2*pair, 2*pair+1).
    // ushort2 LDS writes land on consecutive dwords across the wave (2-way, free).
    {
#pragma unroll
        for (int gg = 0; gg < 2; ++gg) {
            const int g = w * 2 + gg;
#pragma unroll
            for (int i = 0; i < 2; ++i) {
                const int pair = lane + 64 * i;
                if (pair < 80) {
                    const int j = pair * 2;
                    const unsigned short *s0, *s1;
                    if (j < 128) {
                        int tok0 = t0 - 64 + j; if (tok0 < 0) tok0 = 0;
                        int tok1 = t0 - 63 + j; if (tok1 < 0) tok1 = 0;
                        s0 = Vu + (size_t)tok0 * DM + h * 64 + g * 8;
                        s1 = Vu + (size_t)tok1 * DM + h * 64 + g * 8;
                    } else {
                        int c0 = cmin + (j - 128); if (c0 > 127) c0 = 127;
                        int c1 = c0 + 1;           if (c1 > 127) c1 = 127;
                        s0 = CVu + (size_t)c0 * DM + h * 64 + g * 8;
                        s1 = CVu + (size_t)c1 * DM + h * 64 + g * 8;
                    }
                    short8 v0 = *(const short8*)s0;
                    short8 v1 = *(const short8*)s1;
#pragma unroll
                    for (int e = 0; e < 8; ++e) {
                        ushort2 pk;
                        pk.x = (unsigned short)v0[e];
                        pk.y = (unsigned short)v1[e];
                        *(ushort2*)&Vts[(g * 8 + e) * PSTR + j] = pk;
                    }
                }
            }
        }
    }

    const __hip_bfloat16* qp = Q + (size_t)(t0 + w * 16 + l16) * DM + h * 64 + quad * 8;
    short8 qf0 = *(const short8*)(qp);
    short8 qf1 = *(const short8*)(qp + 32);

    f32x4 sc[8];
#pragma unroll
    for (int jt = 0; jt < 8; ++jt) {
        int j = jt * 16 + l16;
        int tok = t0 - 64 + j;
        tok = tok < 0 ? 0 : tok;
        const __hip_bfloat16* kp = K + (size_t)tok * DM + h * 64 + quad * 8;
        short8 b0 = *(const short8*)(kp);
        short8 b1 = *(const short8*)(kp + 32);
        f32x4 a = __builtin_amdgcn_mfma_f32_16x16x32_bf16(qf0, b0, (f32x4){0.f,0.f,0.f,0.f}, 0, 0, 0);
        sc[jt]  = __builtin_amdgcn_mfma_f32_16x16x32_bf16(qf1, b1, a, 0, 0, 0);
    }
    f32x4 sc2[2];
#pragma unroll
    for (int jt = 0; jt < 2; ++jt) {
        int c = cmin + jt * 16 + l16;
        if (c > 127) c = 127;
        const __hip_bfloat16* cp = CK + (size_t)c * DM + h * 64 + quad * 8;
        short8 b0 = *(const short8*)(cp);
        short8 b1 = *(const short8*)(cp + 32);
        f32x4 a = __builtin_amdgcn_mfma_f32_16x16x32_bf16(qf0, b0, (f32x4){0.f,0.f,0.f,0.f}, 0, 0, 0);
        sc2[jt] = __builtin_amdgcn_mfma_f32_16x16x32_bf16(qf1, b1, a, 0, 0, 0);
    }

    __syncthreads();  // all waves' Vts writes visible before PV reads

    const int rbase = w * 16 + quad * 4;
    float gl[4], g2[4];
    float mx[4], sm[4], mx2[4], sm2[4];
#pragma unroll
    for (int reg = 0; reg < 4; ++reg) {
        int rr = rbase + reg;
        int t  = t0 + rr;
        float g = G[t * NH + h];
        int rc = (t >= 96) ? ((t - 64) >> 5) : 0;
        gl[reg] = (t > 0)  ? g        : 0.f;
        g2[reg] = (rc > 0) ? (1.f - g) : 0.f;

        int jlo = rr > (64 - t0) ? rr : (64 - t0);
        int jhi = rr + 63;
        float m = -1e30f;
#pragma unroll
        for (int jt = 0; jt < 8; ++jt) {
            int j = jt * 16 + l16;
            float s = (j >= jlo && j <= jhi) ? sc[jt][reg] * scale : -1e30f;
            sc[jt][reg] = s;
            m = fmaxf(m, s);
        }
        mx[reg] = m;

        int nvis = rc < 16 ? rc : 16;
        int clo = rc - nvis, chi = rc - 1;
        float m2 = -1e30f;
#pragma unroll
        for (int jt = 0; jt < 2; ++jt) {
            int c = cmin + jt * 16 + l16;
            float s = (c >= clo && c <= chi) ? sc2[jt][reg] * scale : -1e30f;
            sc2[jt][reg] = s;
            m2 = fmaxf(m2, s);
        }
        mx2[reg] = m2;
    }
#pragma unroll
    for (int off = 1; off <= 8; off <<= 1)
#pragma unroll
        for (int reg = 0; reg < 4; ++reg) {
            mx[reg]  = fmaxf(mx[reg],  __shfl_xor(mx[reg],  off));
            mx2[reg] = fmaxf(mx2[reg], __shfl_xor(mx2[reg], off));
        }
#pragma unroll
    for (int reg = 0; reg < 4; ++reg) {
        float s = 0.f, s2 = 0.f;
#pragma unroll
        for (int jt = 0; jt < 8; ++jt) {
            float p = __expf(sc[jt][reg] - mx[reg]);
            sc[jt][reg] = p;
            s += p;
        }
#pragma unroll
        for (int jt = 0; jt < 2; ++jt) {
            float p = __expf(sc2[jt][reg] - mx2[reg]);
            sc2[jt][reg] = p;
            s2 += p;
        }
        sm[reg] = s; sm2[reg] = s2;
    }
#pragma unroll
    for (int off = 1; off <= 8; off <<= 1)
#pragma unroll
        for (int reg = 0; reg < 4; ++reg) {
            sm[reg]  += __shfl_xor(sm[reg],  off);
            sm2[reg] += __shfl_xor(sm2[reg], off);
        }

#pragma unroll
    for (int reg = 0; reg < 4; ++reg) {
        float f1 = gl[reg] / sm[reg];
        float f2 = g2[reg] / sm2[reg];
        int rowoff = (rbase + reg) * PSTR;
#pragma unroll
        for (int jt = 0; jt < 8; ++jt) {
            __hip_bfloat16 hb = (__hip_bfloat16)(sc[jt][reg] * f1);
            Pls[rowoff + jt * 16 + l16] = *(unsigned short*)&hb;
        }
#pragma unroll
        for (int jt = 0; jt < 2; ++jt) {
            __hip_bfloat16 hb = (__hip_bfloat16)(sc2[jt][reg] * f2);
            Pls[rowoff + 128 + jt * 16 + l16] = *(unsigned short*)&hb;
        }
    }
    asm volatile("s_waitcnt lgkmcnt(0)" ::: "memory");  // wave-private P round-trip

    f32x4 o[4];
#pragma unroll
    for (int nt = 0; nt < 4; ++nt) o[nt] = (f32x4){0.f, 0.f, 0.f, 0.f};
#pragma unroll
    for (int kt = 0; kt < 5; ++kt) {
        short8 a = *(const short8*)&Pls[(w * 16 + l16) * PSTR + kt * 32 + quad * 8];
#pragma unroll
        for (int nt = 0; nt < 4; ++nt) {
            int dd = nt * 16 + l16;
            short8 b = *(const short8*)&Vts[dd * PSTR + kt * 32 + quad * 8];
            o[nt] = __builtin_amdgcn_mfma_f32_16x16x32_bf16(a, b, o[nt], 0, 0, 0);
        }
    }

#pragma unroll
    for (int nt = 0; nt < 4; ++nt) {
#pragma unroll
        for (int reg = 0; reg < 4; ++reg) {
            int row = t0 + rbase + reg;
            int col = h * 64 + nt * 16 + l16;
            Aout[(size_t)row * DM + col] = (__hip_bfloat16)(o[nt][reg]);
        }
    }
}

extern "C" void kernel_launch(void* const* d_in, const int* in_sizes, int n_in,
                              void* d_out, int out_size, void* d_ws, size_t ws_size,
                              hipStream_t stream)
{
    const float* x  = (const float*)d_in[0];
    const float* Wq = (const float*)d_in[1];
    const float* bq = (const float*)d_in[2];
    const float* Wk = (const float*)d_in[3];
    const float* bk = (const float*)d_in[4];
    const float* Wv = (const float*)d_in[5];
    const float* bv = (const float*)d_in[6];
    const float* Wo = (const float*)d_in[7];
    const float* bo = (const float*)d_in[8];
    const float* Wg = (const float*)d_in[9];
    const float* bg = (const float*)d_in[10];
    float* out = (float*)d_out;

    char* ws = (char*)d_ws;
    const size_t MB = 1024 * 1024;
    __hip_bfloat16* xb  = (__hip_bfloat16*)(ws + 0 * MB);   // 8 MB
    __hip_bfloat16* Qb  = (__hip_bfloat16*)(ws + 8 * MB);   // 8 MB
    __hip_bfloat16* Kb  = (__hip_bfloat16*)(ws + 16 * MB);  // 8 MB
    __hip_bfloat16* Vb  = (__hip_bfloat16*)(ws + 24 * MB);  // 8 MB
    __hip_bfloat16* Ab  = (__hip_bfloat16*)(ws + 32 * MB);  // 8 MB
    __hip_bfloat16* Wqb = (__hip_bfloat16*)(ws + 40 * MB);  // 2 MB
    __hip_bfloat16* Wkb = (__hip_bfloat16*)(ws + 42 * MB);  // 2 MB
    __hip_bfloat16* Wvb = (__hip_bfloat16*)(ws + 44 * MB);  // 2 MB
    __hip_bfloat16* Wob = (__hip_bfloat16*)(ws + 46 * MB);  // 2 MB
    __hip_bfloat16* CKb = (__hip_bfloat16*)(ws + 48 * MB);            // 256 KB
    __hip_bfloat16* CVb = (__hip_bfloat16*)(ws + 48 * MB + 256*1024); // 256 KB
    float* Gf           = (float*)(ws + 48 * MB + 512 * 1024);        // 256 KB
    __hip_bfloat16* Wgb = (__hip_bfloat16*)(ws + 48 * MB + 768*1024); // 32 KB

    cast_all<<<dim3(8208), 256, 0, stream>>>(x, Wq, Wk, Wv, Wo, Wg,
                                             xb, Wqb, Wkb, Wvb, Wob, Wgb);

    // Fused QKV GEMM: grid (32, 24); group = blockIdx.y>>3.
    gemm128<__hip_bfloat16><<<dim3(32, 24), 256, 0, stream>>>(
        xb, Wqb, Wkb, Wvb, bq, bk, bv, Qb, Kb, Vb);
    g_mfma<<<dim3(256), 64, 0, stream>>>(xb, Wgb, bg, Gf);
    chunk_kernel<<<dim3(128, 4), 256, 0, stream>>>(Kb, Vb, CKb, CVb);
    attn_mfma<<<dim3(64, 16), 256, 0, stream>>>(Qb, Kb, Vb, CKb, CVb, Gf, Ab);
    // Output GEMM: 128x64 tiles, grid (32, 16) = 512 blocks.
    gemm_n64<float><<<dim3(32, 16), 256, 0, stream>>>(Ab, Wob, bo, out);
}